// Round 7
// baseline (350.587 us; speedup 1.0000x reference)
//
#include <hip/hip_runtime.h>
#include <math.h>

#define BB 16
#define SS 1024
#define NF 5
#define DD 64
#define HH 8
#define HDIM 8
#define NLAYER 2
#define FFD 128
#define NQ 8
#define QLAY 3
#define NC 3
#define NSWEEP 5

typedef __fp16 hf2 __attribute__((ext_vector_type(2)));
typedef __fp16 h8  __attribute__((ext_vector_type(8)));
typedef float  f4x __attribute__((ext_vector_type(4)));

// ---------------- fast cross-lane helpers ------------
__device__ __forceinline__ int   f2i_(float x) { union { float f; int i; } u; u.f = x; return u.i; }
__device__ __forceinline__ float i2f_(int x)   { union { float f; int i; } u; u.i = x; return u.f; }

// full-wave lane gather: value of lane (pa/4) — pa is a BYTE lane address
// (wave-local, works identically in multi-wave blocks).
__device__ __forceinline__ float bperm_(int pa, float x) {
    return i2f_(__builtin_amdgcn_ds_bpermute(pa, f2i_(x)));
}

// lane ^ 32 via v_permlane32_swap_b32 (VALU-speed). Direction-immune select:
// with both operands = x, the two output words are {x[lane], x[lane^32]} in
// some order; the one bitwise-equal to mine is mine, so take the other.
__device__ __forceinline__ float half32_(float x) {
#if defined(__has_builtin)
#if __has_builtin(__builtin_amdgcn_permlane32_swap)
    int xi = f2i_(x);
    auto r = __builtin_amdgcn_permlane32_swap(xi, xi, false, false);
    int r0 = (int)r[0], r1 = (int)r[1];
    return i2f_(r0 == xi ? r1 : r0);
#else
    return __shfl_xor(x, 32);
#endif
#else
    return __shfl_xor(x, 32);
#endif
}

// compile-time lane-xor: DPP quad_perm (1..3), ds_swizzle bitmode (<32),
// permlane32 (+swizzle) for >=32.
template<int M> __device__ __forceinline__ float lx(float x) {
    if constexpr (M == 0) {
        return x;
    } else if constexpr (M == 1) {       // quad_perm [1,0,3,2]
        return i2f_(__builtin_amdgcn_update_dpp(0, f2i_(x), 0xB1, 0xF, 0xF, true));
    } else if constexpr (M == 2) {       // quad_perm [2,3,0,1]
        return i2f_(__builtin_amdgcn_update_dpp(0, f2i_(x), 0x4E, 0xF, 0xF, true));
    } else if constexpr (M == 3) {       // quad_perm [3,2,1,0]
        return i2f_(__builtin_amdgcn_update_dpp(0, f2i_(x), 0x1B, 0xF, 0xF, true));
    } else if constexpr (M < 32) {       // ds_swizzle bitmode: xor<<10 | and=0x1F
        return i2f_(__builtin_amdgcn_ds_swizzle(f2i_(x), (M << 10) | 0x1F));
    } else {
        return lx<M & 31>(half32_(x));
    }
}

// lane ^ 16 via v_permlane16_swap_b32 (gfx950) — same direction-immune trick;
// fallback is the ds_swizzle path (identical permutation, DS latency).
__device__ __forceinline__ float half16_(float x) {
#if defined(__has_builtin)
#if __has_builtin(__builtin_amdgcn_permlane16_swap)
    int xi = f2i_(x);
    auto r = __builtin_amdgcn_permlane16_swap(xi, xi, false, false);
    int r0 = (int)r[0], r1 = (int)r[1];
    return i2f_(r0 == xi ? r1 : r0);
#else
    return lx<16>(x);
#endif
#else
    return lx<16>(x);
#endif
}

// full 64-lane sum reduce, order 32..1 (matches prior rounds)
__device__ __forceinline__ float wsum64_(float v) {
    v += half32_(v);
    v += half16_(v);
    v += lx<8>(v);
    v += lx<4>(v);
    v += lx<2>(v);
    v += lx<1>(v);
    return v;
}

// native exp2 (v_exp_f32 computes 2^x)
#if defined(__has_builtin)
#if __has_builtin(__builtin_amdgcn_exp2f)
#define EXP2F(x) __builtin_amdgcn_exp2f(x)
#else
#define EXP2F(x) exp2f(x)
#endif
#else
#define EXP2F(x) exp2f(x)
#endif

// Q pre-scale: 1/sqrt(8) folded with log2(e) so attention uses native exp2.
#define QSCALE (0.3535533906f * 1.4426950408889634f)

// ---------------- fused embed + q,k,v projection (layer 0) ------------------
__global__ __launch_bounds__(64) void k_qkv0(const float* __restrict__ x,
                                             const float* __restrict__ Wemb,
                                             const float* __restrict__ bemb,
                                             const float* __restrict__ Wq, const float* __restrict__ bq,
                                             const float* __restrict__ Wk, const float* __restrict__ bk,
                                             const float* __restrict__ Wv, const float* __restrict__ bv,
                                             hf2* __restrict__ qh, hf2* __restrict__ kh,
                                             hf2* __restrict__ vt, float* __restrict__ h) {
    __shared__ float hrow[4][DD];
    int d   = threadIdx.x;
    int bs0 = blockIdx.x * 4;
    {
        int i = d >> 1;
        float div = expf((float)(2 * i) * (-9.210340371976184f / 64.0f));
#pragma unroll
        for (int r = 0; r < 4; ++r) {
            int bs = bs0 + r;
            int s  = bs & (SS - 1);
            const float* xr = x + bs * NF;
            float acc = bemb[d];
#pragma unroll
            for (int f = 0; f < NF; ++f) acc += xr[f] * Wemb[f * DD + d];
            float ang = (float)s * div;
            float pe = (d & 1) ? cosf(ang) : sinf(ang);
            float hv = acc + pe;
            hrow[r][d] = hv;
            h[bs * DD + d] = hv;
        }
    }
    __syncthreads();
    const float* wq = Wq;                 // l = 0
    const float* wk = Wk;
    const float* wv = Wv;
    float aq[4], ak[4], av[4];
    float bqv = bq[d], bkv = bk[d], bvv = bv[d];
#pragma unroll
    for (int r = 0; r < 4; ++r) { aq[r] = bqv; ak[r] = bkv; av[r] = bvv; }
#pragma unroll 4
    for (int i = 0; i < DD; ++i) {
        float wqv = wq[i * DD + d], wkv = wk[i * DD + d], wvv = wv[i * DD + d];
#pragma unroll
        for (int r = 0; r < 4; ++r) {
            float hv = hrow[r][i];
            aq[r] += hv * wqv; ak[r] += hv * wkv; av[r] += hv * wvv;
        }
    }
    int hh = d >> 3, hd = d & 7;
    const float qs = QSCALE;
    float aqp[4], akp[4];
#pragma unroll
    for (int r = 0; r < 4; ++r) { aqp[r] = lx<1>(aq[r]); akp[r] = lx<1>(ak[r]); }
    if ((hd & 1) == 0) {
#pragma unroll
        for (int r = 0; r < 4; ++r) {
            int bs = bs0 + r;
            int b = bs >> 10, s = bs & 1023;
            int bhs = ((b * HH + hh) << 10) | s;
            qh[bhs * 4 + (hd >> 1)] = __builtin_amdgcn_cvt_pkrtz(aq[r] * qs, aqp[r] * qs);
            kh[bhs * 4 + (hd >> 1)] = __builtin_amdgcn_cvt_pkrtz(ak[r], akp[r]);
        }
    }
    {
        int b = bs0 >> 10, s0 = bs0 & 1023;
        int vrow = (b * HH + hh) * 8 + hd;
        hf2* vp = vt + vrow * 512 + (s0 >> 1);
        vp[0] = __builtin_amdgcn_cvt_pkrtz(av[0], av[1]);
        vp[1] = __builtin_amdgcn_cvt_pkrtz(av[2], av[3]);
    }
}

// ---------------- attention via MFMA (swapped-operand, LDS-free) ------------
__global__ __launch_bounds__(256) void k_attn(const float4* __restrict__ qh4,
                                              const float4* __restrict__ kh4,
                                              const float4* __restrict__ vt4,
                                              float* __restrict__ Ao) {
    int bh  = blockIdx.x;             // 0..127
    int sb  = blockIdx.y;             // 0..15
    int tid = threadIdx.x;
    int wv  = tid >> 6;
    int L   = tid & 63;
    int m = L & 15, quad = L >> 4;
    union U { float4 f; h8 h; };
    h8 hz = {0,0,0,0,0,0,0,0};
    h8 bQ = hz;
    if (quad == 0) { U u; u.f = qh4[(bh << 10) | (sb * 64 + wv * 16 + m)]; bQ = u.h; }
    int kmap = 8 * (m >> 2) + (m & 3);
    const float4* kbase = kh4 + (bh << 10);
    const float4* vbase = vt4 + ((bh * 8 + (m & 7)) << 7);
    f4x Oacc = {0.f, 0.f, 0.f, 0.f};
    float ls = 0.f;
    for (int kc = 0; kc < 32; ++kc) {
        h8 aK0 = hz, aK1 = hz;
        if (quad == 0) {
            U u0, u1;
            u0.f = kbase[kc * 32 + kmap];
            u1.f = kbase[kc * 32 + kmap + 4];
            aK0 = u0.h; aK1 = u1.h;
        }
        f4x S0 = {0.f,0.f,0.f,0.f}, S1 = {0.f,0.f,0.f,0.f};
        S0 = __builtin_amdgcn_mfma_f32_16x16x32_f16(aK0, bQ, S0, 0, 0, 0);
        S1 = __builtin_amdgcn_mfma_f32_16x16x32_f16(aK1, bQ, S1, 0, 0, 0);
        // S is in log2 units (Q pre-scaled by 1/sqrt(8)*log2(e)) -> native exp2
        float p0 = EXP2F(S0[0]), p1 = EXP2F(S0[1]);
        float p2 = EXP2F(S0[2]), p3 = EXP2F(S0[3]);
        float p4 = EXP2F(S1[0]), p5 = EXP2F(S1[1]);
        float p6 = EXP2F(S1[2]), p7 = EXP2F(S1[3]);
        ls += (p0 + p1 + p2 + p3) + (p4 + p5 + p6 + p7);
        hf2 c0 = __builtin_amdgcn_cvt_pkrtz(p0, p1);
        hf2 c1 = __builtin_amdgcn_cvt_pkrtz(p2, p3);
        hf2 c2 = __builtin_amdgcn_cvt_pkrtz(p4, p5);
        hf2 c3 = __builtin_amdgcn_cvt_pkrtz(p6, p7);
        h8 aP;
        aP[0] = c0[0]; aP[1] = c0[1]; aP[2] = c1[0]; aP[3] = c1[1];
        aP[4] = c2[0]; aP[5] = c2[1]; aP[6] = c3[0]; aP[7] = c3[1];
        h8 bV = hz;
        if (m < 8) {
            U uv; uv.f = vbase[kc * 4 + quad];
            bV = uv.h;
        }
        Oacc = __builtin_amdgcn_mfma_f32_16x16x32_f16(aP, bV, Oacc, 0, 0, 0);
    }
    ls += half16_(ls);
    ls += half32_(ls);
    float d0 = bperm_((4 * quad + 0) << 2, ls);
    float d1 = bperm_((4 * quad + 1) << 2, ls);
    float d2 = bperm_((4 * quad + 2) << 2, ls);
    float d3 = bperm_((4 * quad + 3) << 2, ls);
    if (m < 8) {
        int srow = sb * 64 + wv * 16 + quad * 4;
        int base = (((bh << 10) | srow) << 3) + m;
        Ao[base]      = Oacc[0] / d0;
        Ao[base + 8]  = Oacc[1] / d1;
        Ao[base + 16] = Oacc[2] / d2;
        Ao[base + 24] = Oacc[3] / d3;
    }
}

// ---------------- fused mid: Oproj + LN1 + FFN1 + FFN2 + LN2 [+ qkv(l+1)] ---
// fuse!=0: also next layer's qkv. fuse==0 (last layer): writes the 4-row
// partial sums for the mean-pool.
__global__ __launch_bounds__(128) void k_mid(const float* __restrict__ Ao,
                                             const float* __restrict__ Wo, const float* __restrict__ bo,
                                             const float* __restrict__ g1, const float* __restrict__ b1,
                                             const float* __restrict__ Wf1, const float* __restrict__ bf1,
                                             const float* __restrict__ Wf2, const float* __restrict__ bf2,
                                             const float* __restrict__ g2, const float* __restrict__ b2,
                                             float* __restrict__ h, int l, int fuse,
                                             const float* __restrict__ Wq, const float* __restrict__ bq,
                                             const float* __restrict__ Wk, const float* __restrict__ bk,
                                             const float* __restrict__ Wv, const float* __restrict__ bv,
                                             hf2* __restrict__ qh, hf2* __restrict__ kh,
                                             hf2* __restrict__ vt, float* __restrict__ pp2) {
    __shared__ float orow[4][DD];
    __shared__ float h1s[4][DD];
    __shared__ float frow[4][FFD];
    __shared__ float hfin[4][DD];
    int t    = threadIdx.x;
    int d    = t & 63;
    int half = t >> 6;
    int bs0  = blockIdx.x * 4;
    int hh = d >> 3, hd = d & 7;
    int r0 = half * 2, r1 = r0 + 1;

#pragma unroll
    for (int rr = 0; rr < 2; ++rr) {
        int r  = r0 + rr;
        int bs = bs0 + r;
        int b = bs >> 10, s = bs & 1023;
        int bhs = ((b * HH + hh) << 10) | s;
        orow[r][d] = Ao[(bhs << 3) + hd];
    }
    __syncthreads();

    {
        const float* w = Wo + l * DD * DD;
        float bias = bo[l * DD + d];
        float acc0 = bias, acc1 = bias;
#pragma unroll 4
        for (int i = 0; i < DD; ++i) {
            float wv = w[i * DD + d];
            acc0 += orow[r0][i] * wv;
            acc1 += orow[r1][i] * wv;
        }
        float gg = g1[l * DD + d], bb = b1[l * DD + d];
        float accs[2] = {acc0, acc1};
#pragma unroll
        for (int rr = 0; rr < 2; ++rr) {
            int r = r0 + rr;
            float a = accs[rr] + h[(bs0 + r) * DD + d];
            float sum = wsum64_(a);
            float mean = sum * (1.f / 64.f);
            float dx = a - mean;
            float vs = wsum64_(dx * dx);
            float rstd = rsqrtf(vs * (1.f / 64.f) + 1e-5f);
            h1s[r][d] = dx * rstd * gg + bb;
        }
    }
    __syncthreads();

    {
        const float* w = Wf1 + l * DD * FFD;
        float bv_ = bf1[l * FFD + t];
        float a0 = bv_, a1 = bv_, a2 = bv_, a3 = bv_;
#pragma unroll 4
        for (int i = 0; i < DD; ++i) {
            float wv = w[i * FFD + t];
            a0 += h1s[0][i]*wv; a1 += h1s[1][i]*wv;
            a2 += h1s[2][i]*wv; a3 += h1s[3][i]*wv;
        }
        frow[0][t] = fmaxf(a0, 0.f); frow[1][t] = fmaxf(a1, 0.f);
        frow[2][t] = fmaxf(a2, 0.f); frow[3][t] = fmaxf(a3, 0.f);
    }
    __syncthreads();

    {
        const float* w = Wf2 + l * FFD * DD;
        float bias = bf2[l * DD + d];
        float acc0 = bias, acc1 = bias;
#pragma unroll 4
        for (int i = 0; i < FFD; ++i) {
            float wv = w[i * DD + d];
            acc0 += frow[r0][i] * wv;
            acc1 += frow[r1][i] * wv;
        }
        float gg = g2[l * DD + d], bb = b2[l * DD + d];
        float accs[2] = {acc0, acc1};
#pragma unroll
        for (int rr = 0; rr < 2; ++rr) {
            int r = r0 + rr;
            float a = accs[rr] + h1s[r][d];
            float sum = wsum64_(a);
            float mean = sum * (1.f / 64.f);
            float dx = a - mean;
            float vs = wsum64_(dx * dx);
            float rstd = rsqrtf(vs * (1.f / 64.f) + 1e-5f);
            float hv = dx * rstd * gg + bb;
            hfin[r][d] = hv;
            h[(bs0 + r) * DD + d] = hv;
        }
    }

    if (!fuse) {
        // last layer: emit 4-row pool partial for this block
        __syncthreads();
        if (t < 64) {
            pp2[blockIdx.x * DD + t] = (hfin[0][t] + hfin[1][t]) + (hfin[2][t] + hfin[3][t]);
        }
        return;
    }

    // ---- fused q,k,v projection for layer l+1 from hfin ----
    __syncthreads();
    const int l1 = l + 1;
    if (t < 64) {
        const float* wq = Wq + l1 * DD * DD;
        const float* wk = Wk + l1 * DD * DD;
        float aq[4], ak[4];
        float bqv = bq[l1 * DD + d], bkv = bk[l1 * DD + d];
#pragma unroll
        for (int r = 0; r < 4; ++r) { aq[r] = bqv; ak[r] = bkv; }
#pragma unroll 4
        for (int i = 0; i < DD; ++i) {
            float wqv = wq[i * DD + d], wkv = wk[i * DD + d];
#pragma unroll
            for (int r = 0; r < 4; ++r) {
                float hv = hfin[r][i];
                aq[r] += hv * wqv; ak[r] += hv * wkv;
            }
        }
        const float qs = QSCALE;
        float aqp[4], akp[4];
#pragma unroll
        for (int r = 0; r < 4; ++r) { aqp[r] = lx<1>(aq[r]); akp[r] = lx<1>(ak[r]); }
        if ((hd & 1) == 0) {
#pragma unroll
            for (int r = 0; r < 4; ++r) {
                int bs = bs0 + r;
                int b = bs >> 10, s = bs & 1023;
                int bhs = ((b * HH + hh) << 10) | s;
                qh[bhs * 4 + (hd >> 1)] = __builtin_amdgcn_cvt_pkrtz(aq[r] * qs, aqp[r] * qs);
                kh[bhs * 4 + (hd >> 1)] = __builtin_amdgcn_cvt_pkrtz(ak[r], akp[r]);
            }
        }
    } else {
        const float* wv = Wv + l1 * DD * DD;
        float av[4];
        float bvv = bv[l1 * DD + d];
#pragma unroll
        for (int r = 0; r < 4; ++r) av[r] = bvv;
#pragma unroll 4
        for (int i = 0; i < DD; ++i) {
            float wvv = wv[i * DD + d];
#pragma unroll
            for (int r = 0; r < 4; ++r) av[r] += hfin[r][i] * wvv;
        }
        int b = bs0 >> 10, s0 = bs0 & 1023;
        int vrow = (b * HH + hh) * 8 + hd;
        hf2* vp = vt + vrow * 512 + (s0 >> 1);
        vp[0] = __builtin_amdgcn_cvt_pkrtz(av[0], av[1]);
        vp[1] = __builtin_amdgcn_cvt_pkrtz(av[2], av[3]);
    }
}

// ---------------- fused tail: ALL 16 batches in ONE block -------------------
// 1024 threads = 16 waves; wave b handles batch b end-to-end (the circuit /
// Jacobi is a 64-lane wave algorithm). One CU fetches the code once (the 16
// separate cold-I$ replays were the round-4/6 floor) and 4 waves/SIMD hide
// each other's DS/VALU latency. Per-wave LDS slices; barriers sync lockstep
// waves at phase boundaries only.
__global__ __launch_bounds__(1024) void k_tail(const float* __restrict__ pp2,
                                               const float* __restrict__ Wp1, const float* __restrict__ bp1,
                                               const float* __restrict__ Wp2, const float* __restrict__ bp2,
                                               const float* __restrict__ qw,
                                               float* __restrict__ out) {
    __shared__ float pool_s[BB][DD];
    __shared__ float hid_s[BB][32];
    __shared__ float ang_s[BB][NQ];
    __shared__ float ucoef[BB][QLAY * 16][8];
    __shared__ float2 Ps2[BB][256];
    int t = threadIdx.x;
    int b = t >> 6;                   // wave index = batch
    int L = t & 63;                   // lane within wave
    int lb4 = L << 2;

    // ---- pooling: wave b sums its 256 partial rows; float4 per lane ----
    {
        int dq4 = L & 15;             // d-quad index (d = 4*dq4 .. 4*dq4+3)
        int j0  = (L >> 4) << 6;      // 4 lane-groups x 64 rows
        const float4* pp4 = (const float4*)pp2 + (((b << 8) + j0) << 4) + dq4;
        float ax = 0.f, ay = 0.f, az = 0.f, aw = 0.f;
#pragma unroll 8
        for (int j = 0; j < 64; ++j) {
            float4 v = pp4[j << 4];
            ax += v.x; ay += v.y; az += v.z; aw += v.w;
        }
        // combine the 4 lane-groups (lane bits 4,5) via VALU permlanes
        ax += half16_(ax); ay += half16_(ay); az += half16_(az); aw += half16_(aw);
        ax += half32_(ax); ay += half32_(ay); az += half32_(az); aw += half32_(aw);
        if (L < 16) {
            pool_s[b][L * 4 + 0] = ax * (1.f / 1024.f);
            pool_s[b][L * 4 + 1] = ay * (1.f / 1024.f);
            pool_s[b][L * 4 + 2] = az * (1.f / 1024.f);
            pool_s[b][L * 4 + 3] = aw * (1.f / 1024.f);
        }
    }
    __syncthreads();
    if (L < 32) {
        float a = bp1[L];
#pragma unroll 8
        for (int i = 0; i < DD; ++i) a += pool_s[b][i] * Wp1[i * 32 + L];
        hid_s[b][L] = fmaxf(a, 0.f);
    }
    __syncthreads();
    if (L < NQ) {
        float a = bp2[L];
#pragma unroll 8
        for (int j = 0; j < 32; ++j) a += hid_s[b][j] * Wp2[j * NQ + L];
        ang_s[b][L] = tanhf(a) * 3.14159265358979f;
    }
    __syncthreads();

    // ---- per-gate 2x2 matrix table (lanes 0..47 of each wave) ----
    if (L < QLAY * 16) {
        int l = L >> 4, g8 = L & 15, w = g8 & 7;
        float u00r, u00i, u01r, u01i, u10r, u10i, u11r, u11i;
        if (g8 < 8) {
            float ha = 0.5f * ang_s[b][w];
            float c = __cosf(ha), s = __sinf(ha);
            u00r = c;   u00i = 0.f; u01r = 0.f; u01i = -s;
            u10r = 0.f; u10i = -s;  u11r = c;   u11i = 0.f;
        } else {
            const float* p3 = qw + (l * NQ + w) * 3;
            float phi = p3[0], th = p3[1], om = p3[2];
            float ct = __cosf(0.5f * th), st = __sinf(0.5f * th);
            float al = 0.5f * (phi + om), be = 0.5f * (phi - om);
            float ca = __cosf(al), sa = __sinf(al), cb = __cosf(be), sb = __sinf(be);
            u00r =  ct * ca; u00i = -ct * sa;
            u01r = -st * cb; u01i = -st * sb;
            u10r =  st * cb; u10i = -st * sb;
            u11r =  ct * ca; u11i =  ct * sa;
        }
        float* up = ucoef[b][L];
        up[0] = u00r; up[1] = u00i; up[2] = u01r; up[3] = u01i;
        up[4] = u10r; up[5] = u10i; up[6] = u11r; up[7] = u11i;
    }
    __syncthreads();

    // ---- quantum circuit (rolled, table-driven), one wave per batch ----
    float ar[4], ai[4];
#pragma unroll
    for (int r = 0; r < 4; ++r) { ar[r] = 0.f; ai[r] = 0.f; }
    if (L == 0) ar[0] = 1.f;

#pragma unroll 1
    for (int l = 0; l < QLAY; ++l) {
#pragma unroll 1
        for (int g8 = 0; g8 < 16; ++g8) {
            const float* up = ucoef[b][(l << 4) | g8];
            float u00r = up[0], u00i = up[1], u01r = up[2], u01i = up[3];
            float u10r = up[4], u10i = up[5], u11r = up[6], u11i = up[7];
            int p = 7 - (g8 & 7);
            if (p >= 6) {
#pragma unroll
                for (int pi_ = 0; pi_ < 2; ++pi_) {
                    int lo = (p == 7) ? pi_ : pi_ * 2;
                    int hi = (p == 7) ? pi_ + 2 : pi_ * 2 + 1;
                    float r0 = ar[lo], m0 = ai[lo], r1 = ar[hi], m1 = ai[hi];
                    ar[lo] = u00r*r0 - u00i*m0 + u01r*r1 - u01i*m1;
                    ai[lo] = u00r*m0 + u00i*r0 + u01r*m1 + u01i*r1;
                    ar[hi] = u10r*r0 - u10i*m0 + u11r*r1 - u11i*m1;
                    ai[hi] = u10r*m0 + u10i*r0 + u11r*m1 + u11i*r1;
                }
            } else {
                int bit = (L >> p) & 1;
                float car = bit ? u11r : u00r, cai = bit ? u11i : u00i;
                float cpr = bit ? u10r : u01r, cpi = bit ? u10i : u01i;
                float pre[4], pim[4];
                if (p == 5) {
#pragma unroll
                    for (int r = 0; r < 4; ++r) { pre[r] = half32_(ar[r]); pim[r] = half32_(ai[r]); }
                } else if (p == 4) {
#pragma unroll
                    for (int r = 0; r < 4; ++r) { pre[r] = half16_(ar[r]); pim[r] = half16_(ai[r]); }
                } else if (p == 3) {
#pragma unroll
                    for (int r = 0; r < 4; ++r) { pre[r] = lx<8>(ar[r]); pim[r] = lx<8>(ai[r]); }
                } else if (p == 2) {
#pragma unroll
                    for (int r = 0; r < 4; ++r) { pre[r] = lx<4>(ar[r]); pim[r] = lx<4>(ai[r]); }
                } else if (p == 1) {
#pragma unroll
                    for (int r = 0; r < 4; ++r) { pre[r] = lx<2>(ar[r]); pim[r] = lx<2>(ai[r]); }
                } else {
#pragma unroll
                    for (int r = 0; r < 4; ++r) { pre[r] = lx<1>(ar[r]); pim[r] = lx<1>(ai[r]); }
                }
#pragma unroll
                for (int r = 0; r < 4; ++r) {
                    float nr = car*ar[r] - cai*ai[r] + cpr*pre[r] - cpi*pim[r];
                    float ni = car*ai[r] + cai*ar[r] + cpr*pim[r] + cpi*pre[r];
                    ar[r] = nr; ai[r] = ni;
                }
            }
        }
        // ---- CNOT ladder ----
        { float t0=ar[2]; ar[2]=ar[3]; ar[3]=t0; t0=ai[2]; ai[2]=ai[3]; ai[3]=t0; }
        ar[1] = half32_(ar[1]); ai[1] = half32_(ai[1]);
        ar[3] = half32_(ar[3]); ai[3] = half32_(ai[3]);
#pragma unroll 1
        for (int w = 2; w <= 6; ++w) {
            int pc = 7 - w, pt = 6 - w;
            bool ctrl = (L >> pc) & 1;
            float swr[4], swi[4];
            if (pt == 4) {
#pragma unroll
                for (int r = 0; r < 4; ++r) { swr[r] = half16_(ar[r]); swi[r] = half16_(ai[r]); }
            } else if (pt == 3) {
#pragma unroll
                for (int r = 0; r < 4; ++r) { swr[r] = lx<8>(ar[r]); swi[r] = lx<8>(ai[r]); }
            } else if (pt == 2) {
#pragma unroll
                for (int r = 0; r < 4; ++r) { swr[r] = lx<4>(ar[r]); swi[r] = lx<4>(ai[r]); }
            } else if (pt == 1) {
#pragma unroll
                for (int r = 0; r < 4; ++r) { swr[r] = lx<2>(ar[r]); swi[r] = lx<2>(ai[r]); }
            } else {
#pragma unroll
                for (int r = 0; r < 4; ++r) { swr[r] = lx<1>(ar[r]); swi[r] = lx<1>(ai[r]); }
            }
#pragma unroll
            for (int r = 0; r < 4; ++r) {
                ar[r] = ctrl ? swr[r] : ar[r];
                ai[r] = ctrl ? swi[r] : ai[r];
            }
        }
        {
            bool ctrl = L & 1;
            float n0r = ctrl ? ar[2] : ar[0], n2r = ctrl ? ar[0] : ar[2];
            float n0i = ctrl ? ai[2] : ai[0], n2i = ctrl ? ai[0] : ai[2];
            float n1r = ctrl ? ar[3] : ar[1], n3r = ctrl ? ar[1] : ar[3];
            float n1i = ctrl ? ai[3] : ai[1], n3i = ctrl ? ai[1] : ai[3];
            ar[0]=n0r; ar[1]=n1r; ar[2]=n2r; ar[3]=n3r;
            ai[0]=n0i; ai[1]=n1i; ai[2]=n2i; ai[3]=n3i;
        }
    }

    // ---- <Z_w>, w=0..2 (static xor ladder) ----
    {
        float p0 = ar[0]*ar[0]+ai[0]*ai[0];
        float p1 = ar[1]*ar[1]+ai[1]*ai[1];
        float p2 = ar[2]*ar[2]+ai[2]*ai[2];
        float p3 = ar[3]*ar[3]+ai[3]*ai[3];
        float z0 = p0 + p1 - p2 - p3;
        float z1 = p0 - p1 + p2 - p3;
        float zs = p0 + p1 + p2 + p3;
        float z2 = (L & 32) ? -zs : zs;
        z0 += lx<1>(z0);   z1 += lx<1>(z1);   z2 += lx<1>(z2);
        z0 += lx<2>(z0);   z1 += lx<2>(z1);   z2 += lx<2>(z2);
        z0 += lx<4>(z0);   z1 += lx<4>(z1);   z2 += lx<4>(z2);
        z0 += lx<8>(z0);   z1 += lx<8>(z1);   z2 += lx<8>(z2);
        z0 += half16_(z0); z1 += half16_(z1); z2 += half16_(z2);
        z0 += half32_(z0); z1 += half32_(z1); z2 += half32_(z2);
        if (L == 0) {
            out[b * NC + 0] = z0;
            out[b * NC + 1] = z1;
            out[b * NC + 2] = z2;
        }
    }

    // ---- hand off psi through LDS, redistribute to column layout ----
#pragma unroll
    for (int r = 0; r < 4; ++r) Ps2[b][(r << 6) | L] = make_float2(ar[r], ai[r]);
    __syncthreads();

    {
        int c   = L >> 2;
        int seg = L & 3;
        float gr[4], gi[4];
#pragma unroll
        for (int j = 0; j < 4; ++j) {
            float2 tv = Ps2[b][(seg * 4 + j) * 16 + c];
            gr[j] = tv.x; gi[j] = tv.y;
        }
        float alm = 0.f;
#pragma unroll
        for (int j = 0; j < 4; ++j) alm += gr[j]*gr[j] + gi[j]*gi[j];
        alm += lx<1>(alm);
        alm += lx<2>(alm);

        // ---- one-sided Jacobi; VALU exchange for masks {16,32,48} ----
#pragma unroll 1
        for (int sweep = 0; sweep < NSWEEP; ++sweep) {
#pragma unroll 1
            for (int m = 1; m <= 15; ++m) {
                int xm = m << 2;          // lane xor mask
                float pgr[4], pgi[4], bep;
                if ((xm & 12) == 0) {
                    if (xm == 16) {
#pragma unroll
                        for (int j = 0; j < 4; ++j) { pgr[j] = half16_(gr[j]); pgi[j] = half16_(gi[j]); }
                        bep = half16_(alm);
                    } else if (xm == 32) {
#pragma unroll
                        for (int j = 0; j < 4; ++j) { pgr[j] = half32_(gr[j]); pgi[j] = half32_(gi[j]); }
                        bep = half32_(alm);
                    } else {  // 48
#pragma unroll
                        for (int j = 0; j < 4; ++j) {
                            pgr[j] = half16_(half32_(gr[j]));
                            pgi[j] = half16_(half32_(gi[j]));
                        }
                        bep = half16_(half32_(alm));
                    }
                } else {
                    int pa = lb4 ^ (xm << 2);
#pragma unroll
                    for (int j = 0; j < 4; ++j) {
                        pgr[j] = bperm_(pa, gr[j]);
                        pgi[j] = bperm_(pa, gi[j]);
                    }
                    bep = bperm_(pa, alm);
                }
                float d = 0.f, e = 0.f;
#pragma unroll
                for (int j = 0; j < 4; ++j) {
                    d += gr[j]*pgr[j] + gi[j]*pgi[j];
                    e += gr[j]*pgi[j] - gi[j]*pgr[j];
                }
                d += lx<1>(d); e += lx<1>(e);
                d += lx<2>(d); e += lx<2>(e);
                float g2 = d*d + e*e;
                float cth = 1.f, sth = 0.f, cph = 1.f, sph = 0.f, gn = 0.f;
                if (g2 > 1e-26f) {
                    gn = __builtin_amdgcn_sqrtf(g2);
                    float ginv = __builtin_amdgcn_rcpf(gn);
                    cph = d * ginv; sph = -e * ginv;
                    float tau = (alm - bep) * (0.5f * ginv);
                    float rr = __builtin_amdgcn_rsqf(1.f + tau*tau);  // 1/sqrt(1+tau^2)
                    // clamp: approx rsq can give |tau|*rr slightly > 1 -> NaN sqrt
                    float co = fminf(fabsf(tau) * rr, 1.0f);          // |cos 2theta|
                    cth = __builtin_amdgcn_sqrtf(0.5f + 0.5f*co);
                    sth = copysignf(__builtin_amdgcn_sqrtf(0.5f - 0.5f*co), tau);
                }
#pragma unroll
                for (int j = 0; j < 4; ++j) {
                    float er = cph*pgr[j] - sph*pgi[j];
                    float ei = cph*pgi[j] + sph*pgr[j];
                    gr[j] = cth * gr[j] + sth * er;
                    gi[j] = cth * gi[j] + sth * ei;
                }
                alm = cth*cth*alm + sth*sth*bep + 2.f*cth*sth*gn;
            }
        }

        // exact final column norm (kills approx-math drift in the running alm)
        float alm2 = 0.f;
#pragma unroll
        for (int j = 0; j < 4; ++j) alm2 += gr[j]*gr[j] + gi[j]*gi[j];
        alm2 += lx<1>(alm2);
        alm2 += lx<2>(alm2);

        float ev = fminf(fmaxf(alm2, 1e-10f), 1.0f);
        float term = -ev * __logf(ev);
        term += lx<4>(term);
        term += lx<8>(term);
        term += half16_(term);
        term += half32_(term);
        if (L == 0) out[BB * NC + b] = term;
    }
}

extern "C" void kernel_launch(void* const* d_in, const int* in_sizes, int n_in,
                              void* d_out, int out_size, void* d_ws, size_t ws_size,
                              hipStream_t stream) {
    const float* x    = (const float*)d_in[0];
    const float* Wemb = (const float*)d_in[1];
    const float* bemb = (const float*)d_in[2];
    const float* Wq   = (const float*)d_in[3];
    const float* bq   = (const float*)d_in[4];
    const float* Wk   = (const float*)d_in[5];
    const float* bk   = (const float*)d_in[6];
    const float* Wv   = (const float*)d_in[7];
    const float* bv   = (const float*)d_in[8];
    const float* Wo   = (const float*)d_in[9];
    const float* bo   = (const float*)d_in[10];
    const float* ln1g = (const float*)d_in[11];
    const float* ln1b = (const float*)d_in[12];
    const float* ln2g = (const float*)d_in[13];
    const float* ln2b = (const float*)d_in[14];
    const float* Wf1  = (const float*)d_in[15];
    const float* bf1  = (const float*)d_in[16];
    const float* Wf2  = (const float*)d_in[17];
    const float* bf2  = (const float*)d_in[18];
    const float* Wp1  = (const float*)d_in[19];
    const float* bp1  = (const float*)d_in[20];
    const float* Wp2  = (const float*)d_in[21];
    const float* bp2  = (const float*)d_in[22];
    const float* qwts = (const float*)d_in[23];
    float* out = (float*)d_out;

    const size_t M = 1u << 20;           // 1M floats = B*S*D
    float* ws   = (float*)d_ws;
    float* h    = ws;                            // 1M floats
    hf2*   qh   = (hf2*)(ws + M);                // 0.5M floats (BHS*8 halves)
    hf2*   kh   = (hf2*)(ws + M + M / 2);        // 0.5M floats
    hf2*   vt   = (hf2*)(ws + 2 * M);            // 0.5M floats
    float* Ao   = ws + 2 * M + M / 2;            // 1M floats (BHS*8)
    float* pp2  = ws + 3 * M + M / 2;            // [4096][64] pool partials

    k_qkv0<<<BB * SS / 4, 64, 0, stream>>>(x, Wemb, bemb, Wq, bq, Wk, bk, Wv, bv,
                                           qh, kh, vt, h);
    k_attn<<<dim3(BB * HH, 16), 256, 0, stream>>>((const float4*)qh, (const float4*)kh,
                                                  (const float4*)vt, Ao);
    k_mid<<<BB * SS / 4, 128, 0, stream>>>(Ao, Wo, bo, ln1g, ln1b,
                                           Wf1, bf1, Wf2, bf2, ln2g, ln2b, h, 0, 1,
                                           Wq, bq, Wk, bk, Wv, bv, qh, kh, vt, pp2);
    k_attn<<<dim3(BB * HH, 16), 256, 0, stream>>>((const float4*)qh, (const float4*)kh,
                                                  (const float4*)vt, Ao);
    k_mid<<<BB * SS / 4, 128, 0, stream>>>(Ao, Wo, bo, ln1g, ln1b,
                                           Wf1, bf1, Wf2, bf2, ln2g, ln2b, h, 1, 0,
                                           Wq, bq, Wk, bk, Wv, bv, qh, kh, vt, pp2);
    k_tail<<<1, 1024, 0, stream>>>(pp2, Wp1, bp1, Wp2, bp2, qwts, out);
}

// Round 8
// 298.309 us; speedup vs baseline: 1.1752x; 1.1752x over previous
//
#include <hip/hip_runtime.h>
#include <math.h>

#define BB 16
#define SS 1024
#define NF 5
#define DD 64
#define HH 8
#define HDIM 8
#define NLAYER 2
#define FFD 128
#define NQ 8
#define QLAY 3
#define NC 3
#define NSWEEP 5

typedef __fp16 hf2 __attribute__((ext_vector_type(2)));
typedef __fp16 h8  __attribute__((ext_vector_type(8)));
typedef float  f4x __attribute__((ext_vector_type(4)));

// ---------------- fast cross-lane helpers ------------
__device__ __forceinline__ int   f2i_(float x) { union { float f; int i; } u; u.f = x; return u.i; }
__device__ __forceinline__ float i2f_(int x)   { union { float f; int i; } u; u.i = x; return u.f; }

// full-wave lane gather: value of lane (pa/4) — pa is a BYTE lane address.
__device__ __forceinline__ float bperm_(int pa, float x) {
    return i2f_(__builtin_amdgcn_ds_bpermute(pa, f2i_(x)));
}

// lane ^ 32 via v_permlane32_swap_b32 (VALU-speed). Direction-immune select:
// with both operands = x, the two output words are {x[lane], x[lane^32]} in
// some order; the one bitwise-equal to mine is mine, so take the other.
// HW-validated (absmax 0.0 in rounds 4/6).
__device__ __forceinline__ float half32_(float x) {
#if defined(__has_builtin)
#if __has_builtin(__builtin_amdgcn_permlane32_swap)
    int xi = f2i_(x);
    auto r = __builtin_amdgcn_permlane32_swap(xi, xi, false, false);
    int r0 = (int)r[0], r1 = (int)r[1];
    return i2f_(r0 == xi ? r1 : r0);
#else
    return __shfl_xor(x, 32);
#endif
#else
    return __shfl_xor(x, 32);
#endif
}

// lane ^ 16 via v_permlane16_swap_b32 — same trick. Fallback: DIRECT swizzle
// (must not route through lx<> to avoid recursion).
__device__ __forceinline__ float half16_(float x) {
#if defined(__has_builtin)
#if __has_builtin(__builtin_amdgcn_permlane16_swap)
    int xi = f2i_(x);
    auto r = __builtin_amdgcn_permlane16_swap(xi, xi, false, false);
    int r0 = (int)r[0], r1 = (int)r[1];
    return i2f_(r0 == xi ? r1 : r0);
#else
    return i2f_(__builtin_amdgcn_ds_swizzle(f2i_(x), (16 << 10) | 0x1F));
#endif
#else
    return i2f_(__builtin_amdgcn_ds_swizzle(f2i_(x), (16 << 10) | 0x1F));
#endif
}

// ALL-VALU compile-time lane-xor.
// bits 0,1: quad_perm. xor7 = row_half_mirror (0x141), xor15 = row_mirror
// (0x140) — 4-bit identity 15-i == i^15, 3-bit 7-i == i^7. Compose:
// xor4 = q3∘hm, xor8 = hm∘mir, xor12 = q3∘mir. bits 4,5: permlane16/32_swap.
template<int M> __device__ __forceinline__ float lx(float x) {
    if constexpr (M == 0) {
        return x;
    } else if constexpr (M == 1) {        // quad_perm [1,0,3,2]
        return i2f_(__builtin_amdgcn_update_dpp(0, f2i_(x), 0xB1, 0xF, 0xF, true));
    } else if constexpr (M == 2) {        // quad_perm [2,3,0,1]
        return i2f_(__builtin_amdgcn_update_dpp(0, f2i_(x), 0x4E, 0xF, 0xF, true));
    } else if constexpr (M == 3) {        // quad_perm [3,2,1,0]
        return i2f_(__builtin_amdgcn_update_dpp(0, f2i_(x), 0x1B, 0xF, 0xF, true));
    } else if constexpr (M == 7) {        // row_half_mirror = xor 7
        return i2f_(__builtin_amdgcn_update_dpp(0, f2i_(x), 0x141, 0xF, 0xF, true));
    } else if constexpr (M == 15) {       // row_mirror = xor 15
        return i2f_(__builtin_amdgcn_update_dpp(0, f2i_(x), 0x140, 0xF, 0xF, true));
    } else if constexpr (M < 8) {         // 4,5,6 = (M^7) ∘ 7
        return lx<M ^ 7>(lx<7>(x));
    } else if constexpr (M < 16) {        // 8..14 = (M^15) ∘ 15
        return lx<M ^ 15>(lx<15>(x));
    } else if constexpr (M < 32) {
        return lx<M & 15>(half16_(x));
    } else {
        return lx<M & 31>(half32_(x));
    }
}

// full 64-lane sum reduce, order 32..1 (matches prior rounds; now all-VALU)
__device__ __forceinline__ float wsum64_(float v) {
    v += half32_(v);
    v += half16_(v);
    v += lx<8>(v);
    v += lx<4>(v);
    v += lx<2>(v);
    v += lx<1>(v);
    return v;
}

// native exp2 (v_exp_f32 computes 2^x)
#if defined(__has_builtin)
#if __has_builtin(__builtin_amdgcn_exp2f)
#define EXP2F(x) __builtin_amdgcn_exp2f(x)
#else
#define EXP2F(x) exp2f(x)
#endif
#else
#define EXP2F(x) exp2f(x)
#endif

// Q pre-scale: 1/sqrt(8) folded with log2(e) so attention uses native exp2.
#define QSCALE (0.3535533906f * 1.4426950408889634f)

// ---------------- fused embed + q,k,v projection (layer 0) ------------------
__global__ __launch_bounds__(64) void k_qkv0(const float* __restrict__ x,
                                             const float* __restrict__ Wemb,
                                             const float* __restrict__ bemb,
                                             const float* __restrict__ Wq, const float* __restrict__ bq,
                                             const float* __restrict__ Wk, const float* __restrict__ bk,
                                             const float* __restrict__ Wv, const float* __restrict__ bv,
                                             hf2* __restrict__ qh, hf2* __restrict__ kh,
                                             hf2* __restrict__ vt, float* __restrict__ h) {
    __shared__ float hrow[4][DD];
    int d   = threadIdx.x;
    int bs0 = blockIdx.x * 4;
    {
        int i = d >> 1;
        float div = expf((float)(2 * i) * (-9.210340371976184f / 64.0f));
#pragma unroll
        for (int r = 0; r < 4; ++r) {
            int bs = bs0 + r;
            int s  = bs & (SS - 1);
            const float* xr = x + bs * NF;
            float acc = bemb[d];
#pragma unroll
            for (int f = 0; f < NF; ++f) acc += xr[f] * Wemb[f * DD + d];
            float ang = (float)s * div;
            float pe = (d & 1) ? cosf(ang) : sinf(ang);
            float hv = acc + pe;
            hrow[r][d] = hv;
            h[bs * DD + d] = hv;
        }
    }
    __syncthreads();
    const float* wq = Wq;                 // l = 0
    const float* wk = Wk;
    const float* wv = Wv;
    float aq[4], ak[4], av[4];
    float bqv = bq[d], bkv = bk[d], bvv = bv[d];
#pragma unroll
    for (int r = 0; r < 4; ++r) { aq[r] = bqv; ak[r] = bkv; av[r] = bvv; }
#pragma unroll 4
    for (int i = 0; i < DD; ++i) {
        float wqv = wq[i * DD + d], wkv = wk[i * DD + d], wvv = wv[i * DD + d];
#pragma unroll
        for (int r = 0; r < 4; ++r) {
            float hv = hrow[r][i];
            aq[r] += hv * wqv; ak[r] += hv * wkv; av[r] += hv * wvv;
        }
    }
    int hh = d >> 3, hd = d & 7;
    const float qs = QSCALE;
    float aqp[4], akp[4];
#pragma unroll
    for (int r = 0; r < 4; ++r) { aqp[r] = lx<1>(aq[r]); akp[r] = lx<1>(ak[r]); }
    if ((hd & 1) == 0) {
#pragma unroll
        for (int r = 0; r < 4; ++r) {
            int bs = bs0 + r;
            int b = bs >> 10, s = bs & 1023;
            int bhs = ((b * HH + hh) << 10) | s;
            qh[bhs * 4 + (hd >> 1)] = __builtin_amdgcn_cvt_pkrtz(aq[r] * qs, aqp[r] * qs);
            kh[bhs * 4 + (hd >> 1)] = __builtin_amdgcn_cvt_pkrtz(ak[r], akp[r]);
        }
    }
    {
        int b = bs0 >> 10, s0 = bs0 & 1023;
        int vrow = (b * HH + hh) * 8 + hd;
        hf2* vp = vt + vrow * 512 + (s0 >> 1);
        vp[0] = __builtin_amdgcn_cvt_pkrtz(av[0], av[1]);
        vp[1] = __builtin_amdgcn_cvt_pkrtz(av[2], av[3]);
    }
}

// ---------------- attention via MFMA (swapped-operand, LDS-free) ------------
__global__ __launch_bounds__(256) void k_attn(const float4* __restrict__ qh4,
                                              const float4* __restrict__ kh4,
                                              const float4* __restrict__ vt4,
                                              float* __restrict__ Ao) {
    int bh  = blockIdx.x;             // 0..127
    int sb  = blockIdx.y;             // 0..15
    int tid = threadIdx.x;
    int wv  = tid >> 6;
    int L   = tid & 63;
    int m = L & 15, quad = L >> 4;
    union U { float4 f; h8 h; };
    h8 hz = {0,0,0,0,0,0,0,0};
    h8 bQ = hz;
    if (quad == 0) { U u; u.f = qh4[(bh << 10) | (sb * 64 + wv * 16 + m)]; bQ = u.h; }
    int kmap = 8 * (m >> 2) + (m & 3);
    const float4* kbase = kh4 + (bh << 10);
    const float4* vbase = vt4 + ((bh * 8 + (m & 7)) << 7);
    f4x Oacc = {0.f, 0.f, 0.f, 0.f};
    float ls = 0.f;
    for (int kc = 0; kc < 32; ++kc) {
        h8 aK0 = hz, aK1 = hz;
        if (quad == 0) {
            U u0, u1;
            u0.f = kbase[kc * 32 + kmap];
            u1.f = kbase[kc * 32 + kmap + 4];
            aK0 = u0.h; aK1 = u1.h;
        }
        f4x S0 = {0.f,0.f,0.f,0.f}, S1 = {0.f,0.f,0.f,0.f};
        S0 = __builtin_amdgcn_mfma_f32_16x16x32_f16(aK0, bQ, S0, 0, 0, 0);
        S1 = __builtin_amdgcn_mfma_f32_16x16x32_f16(aK1, bQ, S1, 0, 0, 0);
        // S is in log2 units (Q pre-scaled by 1/sqrt(8)*log2(e)) -> native exp2
        float p0 = EXP2F(S0[0]), p1 = EXP2F(S0[1]);
        float p2 = EXP2F(S0[2]), p3 = EXP2F(S0[3]);
        float p4 = EXP2F(S1[0]), p5 = EXP2F(S1[1]);
        float p6 = EXP2F(S1[2]), p7 = EXP2F(S1[3]);
        ls += (p0 + p1 + p2 + p3) + (p4 + p5 + p6 + p7);
        hf2 c0 = __builtin_amdgcn_cvt_pkrtz(p0, p1);
        hf2 c1 = __builtin_amdgcn_cvt_pkrtz(p2, p3);
        hf2 c2 = __builtin_amdgcn_cvt_pkrtz(p4, p5);
        hf2 c3 = __builtin_amdgcn_cvt_pkrtz(p6, p7);
        h8 aP;
        aP[0] = c0[0]; aP[1] = c0[1]; aP[2] = c1[0]; aP[3] = c1[1];
        aP[4] = c2[0]; aP[5] = c2[1]; aP[6] = c3[0]; aP[7] = c3[1];
        h8 bV = hz;
        if (m < 8) {
            U uv; uv.f = vbase[kc * 4 + quad];
            bV = uv.h;
        }
        Oacc = __builtin_amdgcn_mfma_f32_16x16x32_f16(aP, bV, Oacc, 0, 0, 0);
    }
    ls += half16_(ls);
    ls += half32_(ls);
    float d0 = bperm_((4 * quad + 0) << 2, ls);
    float d1 = bperm_((4 * quad + 1) << 2, ls);
    float d2 = bperm_((4 * quad + 2) << 2, ls);
    float d3 = bperm_((4 * quad + 3) << 2, ls);
    if (m < 8) {
        int srow = sb * 64 + wv * 16 + quad * 4;
        int base = (((bh << 10) | srow) << 3) + m;
        Ao[base]      = Oacc[0] / d0;
        Ao[base + 8]  = Oacc[1] / d1;
        Ao[base + 16] = Oacc[2] / d2;
        Ao[base + 24] = Oacc[3] / d3;
    }
}

// ---------------- fused mid: Oproj + LN1 + FFN1 + FFN2 + LN2 [+ qkv(l+1)] ---
__global__ __launch_bounds__(128) void k_mid(const float* __restrict__ Ao,
                                             const float* __restrict__ Wo, const float* __restrict__ bo,
                                             const float* __restrict__ g1, const float* __restrict__ b1,
                                             const float* __restrict__ Wf1, const float* __restrict__ bf1,
                                             const float* __restrict__ Wf2, const float* __restrict__ bf2,
                                             const float* __restrict__ g2, const float* __restrict__ b2,
                                             float* __restrict__ h, int l, int fuse,
                                             const float* __restrict__ Wq, const float* __restrict__ bq,
                                             const float* __restrict__ Wk, const float* __restrict__ bk,
                                             const float* __restrict__ Wv, const float* __restrict__ bv,
                                             hf2* __restrict__ qh, hf2* __restrict__ kh,
                                             hf2* __restrict__ vt, float* __restrict__ pp2) {
    __shared__ float orow[4][DD];
    __shared__ float h1s[4][DD];
    __shared__ float frow[4][FFD];
    __shared__ float hfin[4][DD];
    int t    = threadIdx.x;
    int d    = t & 63;
    int half = t >> 6;
    int bs0  = blockIdx.x * 4;
    int hh = d >> 3, hd = d & 7;
    int r0 = half * 2, r1 = r0 + 1;

#pragma unroll
    for (int rr = 0; rr < 2; ++rr) {
        int r  = r0 + rr;
        int bs = bs0 + r;
        int b = bs >> 10, s = bs & 1023;
        int bhs = ((b * HH + hh) << 10) | s;
        orow[r][d] = Ao[(bhs << 3) + hd];
    }
    __syncthreads();

    {
        const float* w = Wo + l * DD * DD;
        float bias = bo[l * DD + d];
        float acc0 = bias, acc1 = bias;
#pragma unroll 4
        for (int i = 0; i < DD; ++i) {
            float wv = w[i * DD + d];
            acc0 += orow[r0][i] * wv;
            acc1 += orow[r1][i] * wv;
        }
        float gg = g1[l * DD + d], bb = b1[l * DD + d];
        float accs[2] = {acc0, acc1};
#pragma unroll
        for (int rr = 0; rr < 2; ++rr) {
            int r = r0 + rr;
            float a = accs[rr] + h[(bs0 + r) * DD + d];
            float sum = wsum64_(a);
            float mean = sum * (1.f / 64.f);
            float dx = a - mean;
            float vs = wsum64_(dx * dx);
            float rstd = rsqrtf(vs * (1.f / 64.f) + 1e-5f);
            h1s[r][d] = dx * rstd * gg + bb;
        }
    }
    __syncthreads();

    {
        const float* w = Wf1 + l * DD * FFD;
        float bv_ = bf1[l * FFD + t];
        float a0 = bv_, a1 = bv_, a2 = bv_, a3 = bv_;
#pragma unroll 4
        for (int i = 0; i < DD; ++i) {
            float wv = w[i * FFD + t];
            a0 += h1s[0][i]*wv; a1 += h1s[1][i]*wv;
            a2 += h1s[2][i]*wv; a3 += h1s[3][i]*wv;
        }
        frow[0][t] = fmaxf(a0, 0.f); frow[1][t] = fmaxf(a1, 0.f);
        frow[2][t] = fmaxf(a2, 0.f); frow[3][t] = fmaxf(a3, 0.f);
    }
    __syncthreads();

    {
        const float* w = Wf2 + l * FFD * DD;
        float bias = bf2[l * DD + d];
        float acc0 = bias, acc1 = bias;
#pragma unroll 4
        for (int i = 0; i < FFD; ++i) {
            float wv = w[i * DD + d];
            acc0 += frow[r0][i] * wv;
            acc1 += frow[r1][i] * wv;
        }
        float gg = g2[l * DD + d], bb = b2[l * DD + d];
        float accs[2] = {acc0, acc1};
#pragma unroll
        for (int rr = 0; rr < 2; ++rr) {
            int r = r0 + rr;
            float a = accs[rr] + h1s[r][d];
            float sum = wsum64_(a);
            float mean = sum * (1.f / 64.f);
            float dx = a - mean;
            float vs = wsum64_(dx * dx);
            float rstd = rsqrtf(vs * (1.f / 64.f) + 1e-5f);
            float hv = dx * rstd * gg + bb;
            hfin[r][d] = hv;
            h[(bs0 + r) * DD + d] = hv;
        }
    }

    if (!fuse) {
        // last layer: emit 4-row pool partial for this block
        __syncthreads();
        if (t < 64) {
            pp2[blockIdx.x * DD + t] = (hfin[0][t] + hfin[1][t]) + (hfin[2][t] + hfin[3][t]);
        }
        return;
    }

    // ---- fused q,k,v projection for layer l+1 from hfin ----
    __syncthreads();
    const int l1 = l + 1;
    if (t < 64) {
        const float* wq = Wq + l1 * DD * DD;
        const float* wk = Wk + l1 * DD * DD;
        float aq[4], ak[4];
        float bqv = bq[l1 * DD + d], bkv = bk[l1 * DD + d];
#pragma unroll
        for (int r = 0; r < 4; ++r) { aq[r] = bqv; ak[r] = bkv; }
#pragma unroll 4
        for (int i = 0; i < DD; ++i) {
            float wqv = wq[i * DD + d], wkv = wk[i * DD + d];
#pragma unroll
            for (int r = 0; r < 4; ++r) {
                float hv = hfin[r][i];
                aq[r] += hv * wqv; ak[r] += hv * wkv;
            }
        }
        const float qs = QSCALE;
        float aqp[4], akp[4];
#pragma unroll
        for (int r = 0; r < 4; ++r) { aqp[r] = lx<1>(aq[r]); akp[r] = lx<1>(ak[r]); }
        if ((hd & 1) == 0) {
#pragma unroll
            for (int r = 0; r < 4; ++r) {
                int bs = bs0 + r;
                int b = bs >> 10, s = bs & 1023;
                int bhs = ((b * HH + hh) << 10) | s;
                qh[bhs * 4 + (hd >> 1)] = __builtin_amdgcn_cvt_pkrtz(aq[r] * qs, aqp[r] * qs);
                kh[bhs * 4 + (hd >> 1)] = __builtin_amdgcn_cvt_pkrtz(ak[r], akp[r]);
            }
        }
    } else {
        const float* wv = Wv + l1 * DD * DD;
        float av[4];
        float bvv = bv[l1 * DD + d];
#pragma unroll
        for (int r = 0; r < 4; ++r) av[r] = bvv;
#pragma unroll 4
        for (int i = 0; i < DD; ++i) {
            float wvv = wv[i * DD + d];
#pragma unroll
            for (int r = 0; r < 4; ++r) av[r] += hfin[r][i] * wvv;
        }
        int b = bs0 >> 10, s0 = bs0 & 1023;
        int vrow = (b * HH + hh) * 8 + hd;
        hf2* vp = vt + vrow * 512 + (s0 >> 1);
        vp[0] = __builtin_amdgcn_cvt_pkrtz(av[0], av[1]);
        vp[1] = __builtin_amdgcn_cvt_pkrtz(av[2], av[3]);
    }
}

// ---------------- fused tail: pool + head + circuit + eigensolver -----------
// 16 blocks (one CU each — round 7 proved single-block contends), 256 thr.
// ALL cross-lane exchanges are VALU now (DPP quad/mirror compositions +
// permlane16/32_swap): zero ds_bpermute/ds_swizzle on the critical path.
__global__ __launch_bounds__(256) void k_tail(const float* __restrict__ pp2,
                                              const float* __restrict__ Wp1, const float* __restrict__ bp1,
                                              const float* __restrict__ Wp2, const float* __restrict__ bp2,
                                              const float* __restrict__ qw,
                                              float* __restrict__ out) {
    __shared__ float4 part4[16][16];
    __shared__ float pool_s[DD];
    __shared__ float hid[32];
    __shared__ float ang_s[NQ];
    __shared__ float ucoef[QLAY * 16][8];
    __shared__ float2 Ps2[256];
    int b = blockIdx.x; int t = threadIdx.x;
    int L = t & 63;

    // ---- Rot-gate table build on wave 1 (depends only on qw) — issued
    //      before pooling so the cold qw loads overlap the pool loads ----
    if (t >= 64 && t < 64 + QLAY * NQ) {
        int e = t - 64; int l = e >> 3, w = e & 7;
        const float* p3 = qw + (l * NQ + w) * 3;
        float phi = p3[0], th = p3[1], om = p3[2];
        float ct = __cosf(0.5f * th), st = __sinf(0.5f * th);
        float al = 0.5f * (phi + om), be = 0.5f * (phi - om);
        float ca = __cosf(al), sa = __sinf(al), cb = __cosf(be), sb = __sinf(be);
        float* up = ucoef[l * 16 + 8 + w];
        up[0] =  ct * ca; up[1] = -ct * sa;
        up[2] = -st * cb; up[3] = -st * sb;
        up[4] =  st * cb; up[5] = -st * sb;
        up[6] =  ct * ca; up[7] =  ct * sa;
    }

    // ---- pooling: 256 threads, float4, fully unrolled (16 loads in flight)
    {
        int dq = t & 15, g = t >> 4;
        const float4* pp4 = (const float4*)pp2 + ((b * 256 + g * 16) << 4) + dq;
        float ax = 0.f, ay = 0.f, az = 0.f, aw = 0.f;
#pragma unroll
        for (int j = 0; j < 16; ++j) {
            float4 v = pp4[j << 4];
            ax += v.x; ay += v.y; az += v.z; aw += v.w;
        }
        part4[g][dq] = make_float4(ax, ay, az, aw);
    }
    __syncthreads();
    if (t < 16) {
        float ax = 0.f, ay = 0.f, az = 0.f, aw = 0.f;
#pragma unroll
        for (int g = 0; g < 16; ++g) {
            float4 v = part4[g][t];
            ax += v.x; ay += v.y; az += v.z; aw += v.w;
        }
        pool_s[t * 4 + 0] = ax * (1.f / 1024.f);
        pool_s[t * 4 + 1] = ay * (1.f / 1024.f);
        pool_s[t * 4 + 2] = az * (1.f / 1024.f);
        pool_s[t * 4 + 3] = aw * (1.f / 1024.f);
    }
    __syncthreads();
    if (t < 32) {
        float a = bp1[t];
#pragma unroll 16
        for (int i = 0; i < DD; ++i) a += pool_s[i] * Wp1[i * 32 + t];
        hid[t] = fmaxf(a, 0.f);
    }
    __syncthreads();
    if (t < NQ) {
        float a = bp2[t];
#pragma unroll 8
        for (int j = 0; j < 32; ++j) a += hid[j] * Wp2[j * NQ + t];
        ang_s[t] = tanhf(a) * 3.14159265358979f;
    }
    __syncthreads();
    // ---- RX-gate table (needs ang_s) ----
    if (t < QLAY * NQ) {
        int l = t >> 3, w = t & 7;
        float ha = 0.5f * ang_s[w];
        float c = __cosf(ha), s = __sinf(ha);
        float* up = ucoef[l * 16 + w];
        up[0] = c;   up[1] = 0.f; up[2] = 0.f; up[3] = -s;
        up[4] = 0.f; up[5] = -s;  up[6] = c;   up[7] = 0.f;
    }
    __syncthreads();

    // ---- quantum circuit (rolled, table-driven), wave 0 only ----
    if (t < 64) {
        float ar[4], ai[4];
#pragma unroll
        for (int r = 0; r < 4; ++r) { ar[r] = 0.f; ai[r] = 0.f; }
        if (L == 0) ar[0] = 1.f;

#pragma unroll 1
        for (int l = 0; l < QLAY; ++l) {
#pragma unroll 1
            for (int g8 = 0; g8 < 16; ++g8) {
                const float* up = ucoef[(l << 4) | g8];
                float u00r = up[0], u00i = up[1], u01r = up[2], u01i = up[3];
                float u10r = up[4], u10i = up[5], u11r = up[6], u11i = up[7];
                int p = 7 - (g8 & 7);
                if (p >= 6) {
#pragma unroll
                    for (int pi_ = 0; pi_ < 2; ++pi_) {
                        int lo = (p == 7) ? pi_ : pi_ * 2;
                        int hi = (p == 7) ? pi_ + 2 : pi_ * 2 + 1;
                        float r0 = ar[lo], m0 = ai[lo], r1 = ar[hi], m1 = ai[hi];
                        ar[lo] = u00r*r0 - u00i*m0 + u01r*r1 - u01i*m1;
                        ai[lo] = u00r*m0 + u00i*r0 + u01r*m1 + u01i*r1;
                        ar[hi] = u10r*r0 - u10i*m0 + u11r*r1 - u11i*m1;
                        ai[hi] = u10r*m0 + u10i*r0 + u11r*m1 + u11i*r1;
                    }
                } else {
                    int bit = (L >> p) & 1;
                    float car = bit ? u11r : u00r, cai = bit ? u11i : u00i;
                    float cpr = bit ? u10r : u01r, cpi = bit ? u10i : u01i;
                    float pre[4], pim[4];
                    if (p == 5) {
#pragma unroll
                        for (int r = 0; r < 4; ++r) { pre[r] = half32_(ar[r]); pim[r] = half32_(ai[r]); }
                    } else if (p == 4) {
#pragma unroll
                        for (int r = 0; r < 4; ++r) { pre[r] = half16_(ar[r]); pim[r] = half16_(ai[r]); }
                    } else if (p == 3) {
#pragma unroll
                        for (int r = 0; r < 4; ++r) { pre[r] = lx<8>(ar[r]); pim[r] = lx<8>(ai[r]); }
                    } else if (p == 2) {
#pragma unroll
                        for (int r = 0; r < 4; ++r) { pre[r] = lx<4>(ar[r]); pim[r] = lx<4>(ai[r]); }
                    } else if (p == 1) {
#pragma unroll
                        for (int r = 0; r < 4; ++r) { pre[r] = lx<2>(ar[r]); pim[r] = lx<2>(ai[r]); }
                    } else {
#pragma unroll
                        for (int r = 0; r < 4; ++r) { pre[r] = lx<1>(ar[r]); pim[r] = lx<1>(ai[r]); }
                    }
#pragma unroll
                    for (int r = 0; r < 4; ++r) {
                        float nr = car*ar[r] - cai*ai[r] + cpr*pre[r] - cpi*pim[r];
                        float ni = car*ai[r] + cai*ar[r] + cpr*pim[r] + cpi*pre[r];
                        ar[r] = nr; ai[r] = ni;
                    }
                }
            }
            // ---- CNOT ladder ----
            { float t0=ar[2]; ar[2]=ar[3]; ar[3]=t0; t0=ai[2]; ai[2]=ai[3]; ai[3]=t0; }
            ar[1] = half32_(ar[1]); ai[1] = half32_(ai[1]);
            ar[3] = half32_(ar[3]); ai[3] = half32_(ai[3]);
#pragma unroll 1
            for (int w = 2; w <= 6; ++w) {
                int pc = 7 - w, pt = 6 - w;
                bool ctrl = (L >> pc) & 1;
                float swr[4], swi[4];
                if (pt == 4) {
#pragma unroll
                    for (int r = 0; r < 4; ++r) { swr[r] = half16_(ar[r]); swi[r] = half16_(ai[r]); }
                } else if (pt == 3) {
#pragma unroll
                    for (int r = 0; r < 4; ++r) { swr[r] = lx<8>(ar[r]); swi[r] = lx<8>(ai[r]); }
                } else if (pt == 2) {
#pragma unroll
                    for (int r = 0; r < 4; ++r) { swr[r] = lx<4>(ar[r]); swi[r] = lx<4>(ai[r]); }
                } else if (pt == 1) {
#pragma unroll
                    for (int r = 0; r < 4; ++r) { swr[r] = lx<2>(ar[r]); swi[r] = lx<2>(ai[r]); }
                } else {
#pragma unroll
                    for (int r = 0; r < 4; ++r) { swr[r] = lx<1>(ar[r]); swi[r] = lx<1>(ai[r]); }
                }
#pragma unroll
                for (int r = 0; r < 4; ++r) {
                    ar[r] = ctrl ? swr[r] : ar[r];
                    ai[r] = ctrl ? swi[r] : ai[r];
                }
            }
            {
                bool ctrl = L & 1;
                float n0r = ctrl ? ar[2] : ar[0], n2r = ctrl ? ar[0] : ar[2];
                float n0i = ctrl ? ai[2] : ai[0], n2i = ctrl ? ai[0] : ai[2];
                float n1r = ctrl ? ar[3] : ar[1], n3r = ctrl ? ar[1] : ar[3];
                float n1i = ctrl ? ai[3] : ai[1], n3i = ctrl ? ai[1] : ai[3];
                ar[0]=n0r; ar[1]=n1r; ar[2]=n2r; ar[3]=n3r;
                ai[0]=n0i; ai[1]=n1i; ai[2]=n2i; ai[3]=n3i;
            }
        }

        // ---- <Z_w>, w=0..2 (static xor ladder, all VALU) ----
        {
            float p0 = ar[0]*ar[0]+ai[0]*ai[0];
            float p1 = ar[1]*ar[1]+ai[1]*ai[1];
            float p2 = ar[2]*ar[2]+ai[2]*ai[2];
            float p3 = ar[3]*ar[3]+ai[3]*ai[3];
            float z0 = p0 + p1 - p2 - p3;
            float z1 = p0 - p1 + p2 - p3;
            float zs = p0 + p1 + p2 + p3;
            float z2 = (L & 32) ? -zs : zs;
            z0 += lx<1>(z0);   z1 += lx<1>(z1);   z2 += lx<1>(z2);
            z0 += lx<2>(z0);   z1 += lx<2>(z1);   z2 += lx<2>(z2);
            z0 += lx<4>(z0);   z1 += lx<4>(z1);   z2 += lx<4>(z2);
            z0 += lx<8>(z0);   z1 += lx<8>(z1);   z2 += lx<8>(z2);
            z0 += half16_(z0); z1 += half16_(z1); z2 += half16_(z2);
            z0 += half32_(z0); z1 += half32_(z1); z2 += half32_(z2);
            if (L == 0) {
                out[b * NC + 0] = z0;
                out[b * NC + 1] = z1;
                out[b * NC + 2] = z2;
            }
        }

        // ---- hand off psi through LDS ----
#pragma unroll
        for (int r = 0; r < 4; ++r) Ps2[(r << 6) | L] = make_float2(ar[r], ai[r]);
    }
    __syncthreads();

    if (t < 64) {
        int c   = L >> 2;
        int seg = L & 3;
        float gr[4], gi[4];
#pragma unroll
        for (int j = 0; j < 4; ++j) {
            float2 tv = Ps2[(seg * 4 + j) * 16 + c];
            gr[j] = tv.x; gi[j] = tv.y;
        }
        float alm = 0.f;
#pragma unroll
        for (int j = 0; j < 4; ++j) alm += gr[j]*gr[j] + gi[j]*gi[j];
        alm += lx<1>(alm);
        alm += lx<2>(alm);

        // ---- one-sided Jacobi: ALL-VALU exchange via uniform bit-decompose
        //      (xor-mask bits 2,3 -> DPP mirror compositions; 4,5 -> permlane)
#pragma unroll 1
        for (int sweep = 0; sweep < NSWEEP; ++sweep) {
#pragma unroll 1
            for (int m = 1; m <= 15; ++m) {
                int xm = m << 2;          // lane xor mask, bits 2..5
                float pv[9];
#pragma unroll
                for (int j = 0; j < 4; ++j) { pv[j] = gr[j]; pv[4 + j] = gi[j]; }
                pv[8] = alm;
                int lowm = xm & 12;
                if (lowm == 4) {
#pragma unroll
                    for (int j = 0; j < 9; ++j) pv[j] = lx<4>(pv[j]);
                } else if (lowm == 8) {
#pragma unroll
                    for (int j = 0; j < 9; ++j) pv[j] = lx<8>(pv[j]);
                } else if (lowm == 12) {
#pragma unroll
                    for (int j = 0; j < 9; ++j) pv[j] = lx<12>(pv[j]);
                }
                if (xm & 16) {
#pragma unroll
                    for (int j = 0; j < 9; ++j) pv[j] = half16_(pv[j]);
                }
                if (xm & 32) {
#pragma unroll
                    for (int j = 0; j < 9; ++j) pv[j] = half32_(pv[j]);
                }
                float d = 0.f, e = 0.f;
#pragma unroll
                for (int j = 0; j < 4; ++j) {
                    d += gr[j]*pv[j] + gi[j]*pv[4 + j];
                    e += gr[j]*pv[4 + j] - gi[j]*pv[j];
                }
                d += lx<1>(d); e += lx<1>(e);
                d += lx<2>(d); e += lx<2>(e);
                float bep = pv[8];
                float g2 = d*d + e*e;
                float cth = 1.f, sth = 0.f, cph = 1.f, sph = 0.f, gn = 0.f;
                if (g2 > 1e-26f) {
                    gn = __builtin_amdgcn_sqrtf(g2);
                    float ginv = __builtin_amdgcn_rcpf(gn);
                    cph = d * ginv; sph = -e * ginv;
                    float tau = (alm - bep) * (0.5f * ginv);
                    float rr = __builtin_amdgcn_rsqf(1.f + tau*tau);
                    // clamp: approx rsq can give |tau|*rr slightly > 1 -> NaN sqrt
                    float co = fminf(fabsf(tau) * rr, 1.0f);
                    cth = __builtin_amdgcn_sqrtf(0.5f + 0.5f*co);
                    sth = copysignf(__builtin_amdgcn_sqrtf(0.5f - 0.5f*co), tau);
                }
#pragma unroll
                for (int j = 0; j < 4; ++j) {
                    float er = cph*pv[j] - sph*pv[4 + j];
                    float ei = cph*pv[4 + j] + sph*pv[j];
                    gr[j] = cth * gr[j] + sth * er;
                    gi[j] = cth * gi[j] + sth * ei;
                }
                alm = cth*cth*alm + sth*sth*bep + 2.f*cth*sth*gn;
            }
        }

        // exact final column norm (kills approx-math drift in the running alm)
        float alm2 = 0.f;
#pragma unroll
        for (int j = 0; j < 4; ++j) alm2 += gr[j]*gr[j] + gi[j]*gi[j];
        alm2 += lx<1>(alm2);
        alm2 += lx<2>(alm2);

        float ev = fminf(fmaxf(alm2, 1e-10f), 1.0f);
        float term = -ev * __logf(ev);
        term += lx<4>(term);
        term += lx<8>(term);
        term += half16_(term);
        term += half32_(term);
        if (L == 0) out[BB * NC + b] = term;
    }
}

extern "C" void kernel_launch(void* const* d_in, const int* in_sizes, int n_in,
                              void* d_out, int out_size, void* d_ws, size_t ws_size,
                              hipStream_t stream) {
    const float* x    = (const float*)d_in[0];
    const float* Wemb = (const float*)d_in[1];
    const float* bemb = (const float*)d_in[2];
    const float* Wq   = (const float*)d_in[3];
    const float* bq   = (const float*)d_in[4];
    const float* Wk   = (const float*)d_in[5];
    const float* bk   = (const float*)d_in[6];
    const float* Wv   = (const float*)d_in[7];
    const float* bv   = (const float*)d_in[8];
    const float* Wo   = (const float*)d_in[9];
    const float* bo   = (const float*)d_in[10];
    const float* ln1g = (const float*)d_in[11];
    const float* ln1b = (const float*)d_in[12];
    const float* ln2g = (const float*)d_in[13];
    const float* ln2b = (const float*)d_in[14];
    const float* Wf1  = (const float*)d_in[15];
    const float* bf1  = (const float*)d_in[16];
    const float* Wf2  = (const float*)d_in[17];
    const float* bf2  = (const float*)d_in[18];
    const float* Wp1  = (const float*)d_in[19];
    const float* bp1  = (const float*)d_in[20];
    const float* Wp2  = (const float*)d_in[21];
    const float* bp2  = (const float*)d_in[22];
    const float* qwts = (const float*)d_in[23];
    float* out = (float*)d_out;

    const size_t M = 1u << 20;           // 1M floats = B*S*D
    float* ws   = (float*)d_ws;
    float* h    = ws;                            // 1M floats
    hf2*   qh   = (hf2*)(ws + M);                // 0.5M floats (BHS*8 halves)
    hf2*   kh   = (hf2*)(ws + M + M / 2);        // 0.5M floats
    hf2*   vt   = (hf2*)(ws + 2 * M);            // 0.5M floats
    float* Ao   = ws + 2 * M + M / 2;            // 1M floats (BHS*8)
    float* pp2  = ws + 3 * M + M / 2;            // [4096][64] pool partials

    k_qkv0<<<BB * SS / 4, 64, 0, stream>>>(x, Wemb, bemb, Wq, bq, Wk, bk, Wv, bv,
                                           qh, kh, vt, h);
    k_attn<<<dim3(BB * HH, 16), 256, 0, stream>>>((const float4*)qh, (const float4*)kh,
                                                  (const float4*)vt, Ao);
    k_mid<<<BB * SS / 4, 128, 0, stream>>>(Ao, Wo, bo, ln1g, ln1b,
                                           Wf1, bf1, Wf2, bf2, ln2g, ln2b, h, 0, 1,
                                           Wq, bq, Wk, bk, Wv, bv, qh, kh, vt, pp2);
    k_attn<<<dim3(BB * HH, 16), 256, 0, stream>>>((const float4*)qh, (const float4*)kh,
                                                  (const float4*)vt, Ao);
    k_mid<<<BB * SS / 4, 128, 0, stream>>>(Ao, Wo, bo, ln1g, ln1b,
                                           Wf1, bf1, Wf2, bf2, ln2g, ln2b, h, 1, 0,
                                           Wq, bq, Wk, bk, Wv, bv, qh, kh, vt, pp2);
    k_tail<<<BB, 256, 0, stream>>>(pp2, Wp1, bp1, Wp2, bp2, qwts, out);
}

// Round 9
// 287.968 us; speedup vs baseline: 1.2175x; 1.0359x over previous
//
#include <hip/hip_runtime.h>
#include <math.h>

#define BB 16
#define SS 1024
#define NF 5
#define DD 64
#define HH 8
#define HDIM 8
#define NLAYER 2
#define FFD 128
#define NQ 8
#define QLAY 3
#define NC 3
#define NSWEEP 5

typedef __fp16 hf2 __attribute__((ext_vector_type(2)));
typedef __fp16 h8  __attribute__((ext_vector_type(8)));
typedef float  f4x __attribute__((ext_vector_type(4)));

// ---------------- fast cross-lane helpers ------------
__device__ __forceinline__ int   f2i_(float x) { union { float f; int i; } u; u.f = x; return u.i; }
__device__ __forceinline__ float i2f_(int x)   { union { float f; int i; } u; u.i = x; return u.f; }

// full-wave lane gather: value of lane (pa/4) — pa is a BYTE lane address.
// For BATCHED multi-value exchanges this pipelines (one latency + issue) and
// measured FASTER than per-value DPP/permlane chains (round-8 lesson).
__device__ __forceinline__ float bperm_(int pa, float x) {
    return i2f_(__builtin_amdgcn_ds_bpermute(pa, f2i_(x)));
}

// lane ^ 32 via v_permlane32_swap_b32 (VALU-speed). Direction-immune select:
// with both operands = x, the two output words are {x[lane], x[lane^32]} in
// some order; the one bitwise-equal to mine is mine, so take the other.
__device__ __forceinline__ float half32_(float x) {
#if defined(__has_builtin)
#if __has_builtin(__builtin_amdgcn_permlane32_swap)
    int xi = f2i_(x);
    auto r = __builtin_amdgcn_permlane32_swap(xi, xi, false, false);
    int r0 = (int)r[0], r1 = (int)r[1];
    return i2f_(r0 == xi ? r1 : r0);
#else
    return __shfl_xor(x, 32);
#endif
#else
    return __shfl_xor(x, 32);
#endif
}

// compile-time lane-xor: DPP quad_perm (1..3), ds_swizzle bitmode (<32),
// permlane32 (+swizzle) for >=32.  (R4 version — best measured.)
template<int M> __device__ __forceinline__ float lx(float x) {
    if constexpr (M == 0) {
        return x;
    } else if constexpr (M == 1) {       // quad_perm [1,0,3,2]
        return i2f_(__builtin_amdgcn_update_dpp(0, f2i_(x), 0xB1, 0xF, 0xF, true));
    } else if constexpr (M == 2) {       // quad_perm [2,3,0,1]
        return i2f_(__builtin_amdgcn_update_dpp(0, f2i_(x), 0x4E, 0xF, 0xF, true));
    } else if constexpr (M == 3) {       // quad_perm [3,2,1,0]
        return i2f_(__builtin_amdgcn_update_dpp(0, f2i_(x), 0x1B, 0xF, 0xF, true));
    } else if constexpr (M < 32) {       // ds_swizzle bitmode: xor<<10 | and=0x1F
        return i2f_(__builtin_amdgcn_ds_swizzle(f2i_(x), (M << 10) | 0x1F));
    } else {
        return lx<M & 31>(half32_(x));
    }
}

// full 64-lane sum reduce, order 32..1 (matches prior rounds)
__device__ __forceinline__ float wsum64_(float v) {
    v += lx<32>(v);
    v += lx<16>(v);
    v += lx<8>(v);
    v += lx<4>(v);
    v += lx<2>(v);
    v += lx<1>(v);
    return v;
}

// native exp2 (v_exp_f32 computes 2^x)
#if defined(__has_builtin)
#if __has_builtin(__builtin_amdgcn_exp2f)
#define EXP2F(x) __builtin_amdgcn_exp2f(x)
#else
#define EXP2F(x) exp2f(x)
#endif
#else
#define EXP2F(x) exp2f(x)
#endif

// Q pre-scale: 1/sqrt(8) folded with log2(e) so attention uses native exp2.
#define QSCALE (0.3535533906f * 1.4426950408889634f)

// ---------------- fused embed + q,k,v projection (layer 0) ------------------
__global__ __launch_bounds__(64) void k_qkv0(const float* __restrict__ x,
                                             const float* __restrict__ Wemb,
                                             const float* __restrict__ bemb,
                                             const float* __restrict__ Wq, const float* __restrict__ bq,
                                             const float* __restrict__ Wk, const float* __restrict__ bk,
                                             const float* __restrict__ Wv, const float* __restrict__ bv,
                                             hf2* __restrict__ qh, hf2* __restrict__ kh,
                                             hf2* __restrict__ vt, float* __restrict__ h) {
    __shared__ float hrow[4][DD];
    int d   = threadIdx.x;
    int bs0 = blockIdx.x * 4;
    {
        int i = d >> 1;
        float div = expf((float)(2 * i) * (-9.210340371976184f / 64.0f));
#pragma unroll
        for (int r = 0; r < 4; ++r) {
            int bs = bs0 + r;
            int s  = bs & (SS - 1);
            const float* xr = x + bs * NF;
            float acc = bemb[d];
#pragma unroll
            for (int f = 0; f < NF; ++f) acc += xr[f] * Wemb[f * DD + d];
            float ang = (float)s * div;
            float pe = (d & 1) ? cosf(ang) : sinf(ang);
            float hv = acc + pe;
            hrow[r][d] = hv;
            h[bs * DD + d] = hv;
        }
    }
    __syncthreads();
    const float* wq = Wq;                 // l = 0
    const float* wk = Wk;
    const float* wv = Wv;
    float aq[4], ak[4], av[4];
    float bqv = bq[d], bkv = bk[d], bvv = bv[d];
#pragma unroll
    for (int r = 0; r < 4; ++r) { aq[r] = bqv; ak[r] = bkv; av[r] = bvv; }
#pragma unroll 4
    for (int i = 0; i < DD; ++i) {
        float wqv = wq[i * DD + d], wkv = wk[i * DD + d], wvv = wv[i * DD + d];
#pragma unroll
        for (int r = 0; r < 4; ++r) {
            float hv = hrow[r][i];
            aq[r] += hv * wqv; ak[r] += hv * wkv; av[r] += hv * wvv;
        }
    }
    int hh = d >> 3, hd = d & 7;
    const float qs = QSCALE;
    float aqp[4], akp[4];
#pragma unroll
    for (int r = 0; r < 4; ++r) { aqp[r] = lx<1>(aq[r]); akp[r] = lx<1>(ak[r]); }
    if ((hd & 1) == 0) {
#pragma unroll
        for (int r = 0; r < 4; ++r) {
            int bs = bs0 + r;
            int b = bs >> 10, s = bs & 1023;
            int bhs = ((b * HH + hh) << 10) | s;
            qh[bhs * 4 + (hd >> 1)] = __builtin_amdgcn_cvt_pkrtz(aq[r] * qs, aqp[r] * qs);
            kh[bhs * 4 + (hd >> 1)] = __builtin_amdgcn_cvt_pkrtz(ak[r], akp[r]);
        }
    }
    {
        int b = bs0 >> 10, s0 = bs0 & 1023;
        int vrow = (b * HH + hh) * 8 + hd;
        hf2* vp = vt + vrow * 512 + (s0 >> 1);
        vp[0] = __builtin_amdgcn_cvt_pkrtz(av[0], av[1]);
        vp[1] = __builtin_amdgcn_cvt_pkrtz(av[2], av[3]);
    }
}

// ---------------- attention via MFMA (swapped-operand, LDS-free) ------------
__global__ __launch_bounds__(256) void k_attn(const float4* __restrict__ qh4,
                                              const float4* __restrict__ kh4,
                                              const float4* __restrict__ vt4,
                                              float* __restrict__ Ao) {
    int bh  = blockIdx.x;             // 0..127
    int sb  = blockIdx.y;             // 0..15
    int tid = threadIdx.x;
    int wv  = tid >> 6;
    int L   = tid & 63;
    int m = L & 15, quad = L >> 4;
    union U { float4 f; h8 h; };
    h8 hz = {0,0,0,0,0,0,0,0};
    h8 bQ = hz;
    if (quad == 0) { U u; u.f = qh4[(bh << 10) | (sb * 64 + wv * 16 + m)]; bQ = u.h; }
    int kmap = 8 * (m >> 2) + (m & 3);
    const float4* kbase = kh4 + (bh << 10);
    const float4* vbase = vt4 + ((bh * 8 + (m & 7)) << 7);
    f4x Oacc = {0.f, 0.f, 0.f, 0.f};
    float ls = 0.f;
    for (int kc = 0; kc < 32; ++kc) {
        h8 aK0 = hz, aK1 = hz;
        if (quad == 0) {
            U u0, u1;
            u0.f = kbase[kc * 32 + kmap];
            u1.f = kbase[kc * 32 + kmap + 4];
            aK0 = u0.h; aK1 = u1.h;
        }
        f4x S0 = {0.f,0.f,0.f,0.f}, S1 = {0.f,0.f,0.f,0.f};
        S0 = __builtin_amdgcn_mfma_f32_16x16x32_f16(aK0, bQ, S0, 0, 0, 0);
        S1 = __builtin_amdgcn_mfma_f32_16x16x32_f16(aK1, bQ, S1, 0, 0, 0);
        // S is in log2 units (Q pre-scaled by 1/sqrt(8)*log2(e)) -> native exp2
        float p0 = EXP2F(S0[0]), p1 = EXP2F(S0[1]);
        float p2 = EXP2F(S0[2]), p3 = EXP2F(S0[3]);
        float p4 = EXP2F(S1[0]), p5 = EXP2F(S1[1]);
        float p6 = EXP2F(S1[2]), p7 = EXP2F(S1[3]);
        ls += (p0 + p1 + p2 + p3) + (p4 + p5 + p6 + p7);
        hf2 c0 = __builtin_amdgcn_cvt_pkrtz(p0, p1);
        hf2 c1 = __builtin_amdgcn_cvt_pkrtz(p2, p3);
        hf2 c2 = __builtin_amdgcn_cvt_pkrtz(p4, p5);
        hf2 c3 = __builtin_amdgcn_cvt_pkrtz(p6, p7);
        h8 aP;
        aP[0] = c0[0]; aP[1] = c0[1]; aP[2] = c1[0]; aP[3] = c1[1];
        aP[4] = c2[0]; aP[5] = c2[1]; aP[6] = c3[0]; aP[7] = c3[1];
        h8 bV = hz;
        if (m < 8) {
            U uv; uv.f = vbase[kc * 4 + quad];
            bV = uv.h;
        }
        Oacc = __builtin_amdgcn_mfma_f32_16x16x32_f16(aP, bV, Oacc, 0, 0, 0);
    }
    ls += lx<16>(ls);
    ls += lx<32>(ls);
    float d0 = bperm_((4 * quad + 0) << 2, ls);
    float d1 = bperm_((4 * quad + 1) << 2, ls);
    float d2 = bperm_((4 * quad + 2) << 2, ls);
    float d3 = bperm_((4 * quad + 3) << 2, ls);
    if (m < 8) {
        int srow = sb * 64 + wv * 16 + quad * 4;
        int base = (((bh << 10) | srow) << 3) + m;
        Ao[base]      = Oacc[0] / d0;
        Ao[base + 8]  = Oacc[1] / d1;
        Ao[base + 16] = Oacc[2] / d2;
        Ao[base + 24] = Oacc[3] / d3;
    }
}

// ---------------- fused mid: Oproj + LN1 + FFN1 + FFN2 + LN2 [+ qkv(l+1)] ---
__global__ __launch_bounds__(128) void k_mid(const float* __restrict__ Ao,
                                             const float* __restrict__ Wo, const float* __restrict__ bo,
                                             const float* __restrict__ g1, const float* __restrict__ b1,
                                             const float* __restrict__ Wf1, const float* __restrict__ bf1,
                                             const float* __restrict__ Wf2, const float* __restrict__ bf2,
                                             const float* __restrict__ g2, const float* __restrict__ b2,
                                             float* __restrict__ h, int l, int fuse,
                                             const float* __restrict__ Wq, const float* __restrict__ bq,
                                             const float* __restrict__ Wk, const float* __restrict__ bk,
                                             const float* __restrict__ Wv, const float* __restrict__ bv,
                                             hf2* __restrict__ qh, hf2* __restrict__ kh,
                                             hf2* __restrict__ vt) {
    __shared__ float orow[4][DD];
    __shared__ float h1s[4][DD];
    __shared__ float frow[4][FFD];
    __shared__ float hfin[4][DD];
    int t    = threadIdx.x;
    int d    = t & 63;
    int half = t >> 6;
    int bs0  = blockIdx.x * 4;
    int hh = d >> 3, hd = d & 7;
    int r0 = half * 2, r1 = r0 + 1;

#pragma unroll
    for (int rr = 0; rr < 2; ++rr) {
        int r  = r0 + rr;
        int bs = bs0 + r;
        int b = bs >> 10, s = bs & 1023;
        int bhs = ((b * HH + hh) << 10) | s;
        orow[r][d] = Ao[(bhs << 3) + hd];
    }
    __syncthreads();

    {
        const float* w = Wo + l * DD * DD;
        float bias = bo[l * DD + d];
        float acc0 = bias, acc1 = bias;
#pragma unroll 4
        for (int i = 0; i < DD; ++i) {
            float wv = w[i * DD + d];
            acc0 += orow[r0][i] * wv;
            acc1 += orow[r1][i] * wv;
        }
        float gg = g1[l * DD + d], bb = b1[l * DD + d];
        float accs[2] = {acc0, acc1};
#pragma unroll
        for (int rr = 0; rr < 2; ++rr) {
            int r = r0 + rr;
            float a = accs[rr] + h[(bs0 + r) * DD + d];
            float sum = wsum64_(a);
            float mean = sum * (1.f / 64.f);
            float dx = a - mean;
            float vs = wsum64_(dx * dx);
            float rstd = rsqrtf(vs * (1.f / 64.f) + 1e-5f);
            h1s[r][d] = dx * rstd * gg + bb;
        }
    }
    __syncthreads();

    {
        const float* w = Wf1 + l * DD * FFD;
        float bv_ = bf1[l * FFD + t];
        float a0 = bv_, a1 = bv_, a2 = bv_, a3 = bv_;
#pragma unroll 4
        for (int i = 0; i < DD; ++i) {
            float wv = w[i * FFD + t];
            a0 += h1s[0][i]*wv; a1 += h1s[1][i]*wv;
            a2 += h1s[2][i]*wv; a3 += h1s[3][i]*wv;
        }
        frow[0][t] = fmaxf(a0, 0.f); frow[1][t] = fmaxf(a1, 0.f);
        frow[2][t] = fmaxf(a2, 0.f); frow[3][t] = fmaxf(a3, 0.f);
    }
    __syncthreads();

    {
        const float* w = Wf2 + l * FFD * DD;
        float bias = bf2[l * DD + d];
        float acc0 = bias, acc1 = bias;
#pragma unroll 4
        for (int i = 0; i < FFD; ++i) {
            float wv = w[i * DD + d];
            acc0 += frow[r0][i] * wv;
            acc1 += frow[r1][i] * wv;
        }
        float gg = g2[l * DD + d], bb = b2[l * DD + d];
        float accs[2] = {acc0, acc1};
#pragma unroll
        for (int rr = 0; rr < 2; ++rr) {
            int r = r0 + rr;
            float a = accs[rr] + h1s[r][d];
            float sum = wsum64_(a);
            float mean = sum * (1.f / 64.f);
            float dx = a - mean;
            float vs = wsum64_(dx * dx);
            float rstd = rsqrtf(vs * (1.f / 64.f) + 1e-5f);
            float hv = dx * rstd * gg + bb;
            hfin[r][d] = hv;
            h[(bs0 + r) * DD + d] = hv;
        }
    }

    if (!fuse) return;

    // ---- fused q,k,v projection for layer l+1 from hfin ----
    __syncthreads();
    const int l1 = l + 1;
    if (t < 64) {
        const float* wq = Wq + l1 * DD * DD;
        const float* wk = Wk + l1 * DD * DD;
        float aq[4], ak[4];
        float bqv = bq[l1 * DD + d], bkv = bk[l1 * DD + d];
#pragma unroll
        for (int r = 0; r < 4; ++r) { aq[r] = bqv; ak[r] = bkv; }
#pragma unroll 4
        for (int i = 0; i < DD; ++i) {
            float wqv = wq[i * DD + d], wkv = wk[i * DD + d];
#pragma unroll
            for (int r = 0; r < 4; ++r) {
                float hv = hfin[r][i];
                aq[r] += hv * wqv; ak[r] += hv * wkv;
            }
        }
        const float qs = QSCALE;
        float aqp[4], akp[4];
#pragma unroll
        for (int r = 0; r < 4; ++r) { aqp[r] = lx<1>(aq[r]); akp[r] = lx<1>(ak[r]); }
        if ((hd & 1) == 0) {
#pragma unroll
            for (int r = 0; r < 4; ++r) {
                int bs = bs0 + r;
                int b = bs >> 10, s = bs & 1023;
                int bhs = ((b * HH + hh) << 10) | s;
                qh[bhs * 4 + (hd >> 1)] = __builtin_amdgcn_cvt_pkrtz(aq[r] * qs, aqp[r] * qs);
                kh[bhs * 4 + (hd >> 1)] = __builtin_amdgcn_cvt_pkrtz(ak[r], akp[r]);
            }
        }
    } else {
        const float* wv = Wv + l1 * DD * DD;
        float av[4];
        float bvv = bv[l1 * DD + d];
#pragma unroll
        for (int r = 0; r < 4; ++r) av[r] = bvv;
#pragma unroll 4
        for (int i = 0; i < DD; ++i) {
            float wvv = wv[i * DD + d];
#pragma unroll
            for (int r = 0; r < 4; ++r) av[r] += hfin[r][i] * wvv;
        }
        int b = bs0 >> 10, s0 = bs0 & 1023;
        int vrow = (b * HH + hh) * 8 + hd;
        hf2* vp = vt + vrow * 512 + (s0 >> 1);
        vp[0] = __builtin_amdgcn_cvt_pkrtz(av[0], av[1]);
        vp[1] = __builtin_amdgcn_cvt_pkrtz(av[2], av[3]);
    }
}

// ---------------- fused tail: pool + head + circuit + eigensolver -----------
// EXACT round-4 structure (best measured, 46.5us): rolled single-path bperm
// circuit + bperm Jacobi + t-formula rotation. Only delta: Rot-gate table
// built on wave 1 BEFORE pooling so its cold qw load overlaps the pool.
__global__ __launch_bounds__(256) void k_tail(const float* __restrict__ h,
                                              const float* __restrict__ Wp1, const float* __restrict__ bp1,
                                              const float* __restrict__ Wp2, const float* __restrict__ bp2,
                                              const float* __restrict__ qw,
                                              float* __restrict__ out) {
    __shared__ float part[4][DD];
    __shared__ float pool_s[DD];
    __shared__ float hid[32];
    __shared__ float ang_s[NQ];
    __shared__ float ucoef[QLAY * 16][8];
    __shared__ float2 Ps2[256];
    int b = blockIdx.x; int t = threadIdx.x;
    int L = t;                        // lane id within wave 0 when t<64
    int lb4 = (t & 63) << 2;

    // ---- Rot-gate table on wave 1 (depends only on qw): overlaps pooling ----
    if (t >= 64 && t < 64 + QLAY * NQ) {
        int e = t - 64; int l = e >> 3, w = e & 7;
        const float* p3 = qw + (l * NQ + w) * 3;
        float phi = p3[0], th = p3[1], om = p3[2];
        float ct = __cosf(0.5f * th), st = __sinf(0.5f * th);
        float al = 0.5f * (phi + om), be = 0.5f * (phi - om);
        float ca = __cosf(al), sa = __sinf(al), cb = __cosf(be), sb = __sinf(be);
        float* up = ucoef[l * 16 + 8 + w];
        up[0] =  ct * ca; up[1] = -ct * sa;
        up[2] = -st * cb; up[3] = -st * sb;
        up[4] =  st * cb; up[5] = -st * sb;
        up[6] =  ct * ca; up[7] =  ct * sa;
    }

    // ---- pooling: 4 chunks x 64 d, 256 rows each ----
    {
        int d = t & 63, ch = t >> 6;
        const float* hp = h + (b * SS + ch * 256) * DD + d;
        float acc = 0.f;
#pragma unroll 8
        for (int s = 0; s < 256; ++s) acc += hp[s * DD];
        part[ch][d] = acc;
    }
    __syncthreads();
    if (t < 64) pool_s[t] = (part[0][t] + part[1][t] + part[2][t] + part[3][t]) * (1.f / 1024.f);
    __syncthreads();
    if (t < 32) {
        float a = bp1[t];
#pragma unroll 8
        for (int i = 0; i < DD; ++i) a += pool_s[i] * Wp1[i * 32 + t];
        hid[t] = fmaxf(a, 0.f);
    }
    __syncthreads();
    if (t < NQ) {
        float a = bp2[t];
#pragma unroll 8
        for (int j = 0; j < 32; ++j) a += hid[j] * Wp2[j * NQ + t];
        ang_s[t] = tanhf(a) * 3.14159265358979f;
    }
    __syncthreads();

    // ---- RX-gate table (needs ang_s) ----
    if (t < QLAY * NQ) {
        int l = t >> 3, w = t & 7;
        float ha = 0.5f * ang_s[w];
        float c = __cosf(ha), s = __sinf(ha);
        float* up = ucoef[l * 16 + w];
        up[0] = c;   up[1] = 0.f; up[2] = 0.f; up[3] = -s;
        up[4] = 0.f; up[5] = -s;  up[6] = c;   up[7] = 0.f;
    }
    __syncthreads();

    // ---- quantum circuit (rolled, table-driven) — wave 0 only ----
    float ar[4], ai[4];
#pragma unroll
    for (int r = 0; r < 4; ++r) { ar[r] = 0.f; ai[r] = 0.f; }
    if (L == 0) ar[0] = 1.f;

    if (t < 64) {
#pragma unroll 1
        for (int l = 0; l < QLAY; ++l) {
#pragma unroll 1
            for (int g8 = 0; g8 < 16; ++g8) {
                const float* up = ucoef[(l << 4) | g8];
                float u00r = up[0], u00i = up[1], u01r = up[2], u01i = up[3];
                float u10r = up[4], u10i = up[5], u11r = up[6], u11i = up[7];
                int p = 7 - (g8 & 7);
                if (p >= 6) {
#pragma unroll
                    for (int pi_ = 0; pi_ < 2; ++pi_) {
                        int lo = (p == 7) ? pi_ : pi_ * 2;
                        int hi = (p == 7) ? pi_ + 2 : pi_ * 2 + 1;
                        float r0 = ar[lo], m0 = ai[lo], r1 = ar[hi], m1 = ai[hi];
                        ar[lo] = u00r*r0 - u00i*m0 + u01r*r1 - u01i*m1;
                        ai[lo] = u00r*m0 + u00i*r0 + u01r*m1 + u01i*r1;
                        ar[hi] = u10r*r0 - u10i*m0 + u11r*r1 - u11i*m1;
                        ai[hi] = u10r*m0 + u10i*r0 + u11r*m1 + u11i*r1;
                    }
                } else {
                    int pa  = lb4 ^ (4 << p);
                    int bit = (L >> p) & 1;
                    float car = bit ? u11r : u00r, cai = bit ? u11i : u00i;
                    float cpr = bit ? u10r : u01r, cpi = bit ? u10i : u01i;
#pragma unroll
                    for (int r = 0; r < 4; ++r) {
                        float pre = bperm_(pa, ar[r]);
                        float pim = bperm_(pa, ai[r]);
                        float nr = car*ar[r] - cai*ai[r] + cpr*pre - cpi*pim;
                        float ni = car*ai[r] + cai*ar[r] + cpr*pim + cpi*pre;
                        ar[r] = nr; ai[r] = ni;
                    }
                }
            }
            // ---- CNOT ladder ----
            { float t0=ar[2]; ar[2]=ar[3]; ar[3]=t0; t0=ai[2]; ai[2]=ai[3]; ai[3]=t0; }
            ar[1] = half32_(ar[1]); ai[1] = half32_(ai[1]);
            ar[3] = half32_(ar[3]); ai[3] = half32_(ai[3]);
#pragma unroll 1
            for (int w = 2; w <= 6; ++w) {
                int pc = 7 - w, pt = 6 - w;
                int pa = lb4 ^ (4 << pt);
                bool ctrl = (L >> pc) & 1;
#pragma unroll
                for (int r = 0; r < 4; ++r) {
                    float swr = bperm_(pa, ar[r]);
                    float swi = bperm_(pa, ai[r]);
                    ar[r] = ctrl ? swr : ar[r];
                    ai[r] = ctrl ? swi : ai[r];
                }
            }
            {
                bool ctrl = L & 1;
                float n0r = ctrl ? ar[2] : ar[0], n2r = ctrl ? ar[0] : ar[2];
                float n0i = ctrl ? ai[2] : ai[0], n2i = ctrl ? ai[0] : ai[2];
                float n1r = ctrl ? ar[3] : ar[1], n3r = ctrl ? ar[1] : ar[3];
                float n1i = ctrl ? ai[3] : ai[1], n3i = ctrl ? ai[1] : ai[3];
                ar[0]=n0r; ar[1]=n1r; ar[2]=n2r; ar[3]=n3r;
                ai[0]=n0i; ai[1]=n1i; ai[2]=n2i; ai[3]=n3i;
            }
        }

        // ---- <Z_w>, w=0..2 ----
        {
            float p0 = ar[0]*ar[0]+ai[0]*ai[0];
            float p1 = ar[1]*ar[1]+ai[1]*ai[1];
            float p2 = ar[2]*ar[2]+ai[2]*ai[2];
            float p3 = ar[3]*ar[3]+ai[3]*ai[3];
            float z0 = p0 + p1 - p2 - p3;
            float z1 = p0 - p1 + p2 - p3;
            float zs = p0 + p1 + p2 + p3;
            float z2 = (L & 32) ? -zs : zs;
#pragma unroll 1
            for (int off = 1; off < 64; off <<= 1) {
                int pa = lb4 ^ (off << 2);
                z0 += bperm_(pa, z0);
                z1 += bperm_(pa, z1);
                z2 += bperm_(pa, z2);
            }
            if (L == 0) {
                out[b * NC + 0] = z0;
                out[b * NC + 1] = z1;
                out[b * NC + 2] = z2;
            }
        }

        // ---- hand off psi through LDS ----
#pragma unroll
        for (int r = 0; r < 4; ++r) Ps2[(r << 6) | L] = make_float2(ar[r], ai[r]);
    }
    __syncthreads();

    if (t < 64) {
        int c   = L >> 2;
        int seg = L & 3;
        float gr[4], gi[4];
#pragma unroll
        for (int j = 0; j < 4; ++j) {
            float2 tv = Ps2[(seg * 4 + j) * 16 + c];
            gr[j] = tv.x; gi[j] = tv.y;
        }
        float alm = 0.f;
#pragma unroll
        for (int j = 0; j < 4; ++j) alm += gr[j]*gr[j] + gi[j]*gi[j];
        alm += lx<1>(alm);
        alm += lx<2>(alm);

#pragma unroll 1
        for (int sweep = 0; sweep < NSWEEP; ++sweep) {
#pragma unroll 1
            for (int m = 1; m <= 15; ++m) {
                int pa = lb4 ^ (m << 4);
                float pgr[4], pgi[4];
#pragma unroll
                for (int j = 0; j < 4; ++j) {
                    pgr[j] = bperm_(pa, gr[j]);
                    pgi[j] = bperm_(pa, gi[j]);
                }
                float bep = bperm_(pa, alm);
                float d = 0.f, e = 0.f;
#pragma unroll
                for (int j = 0; j < 4; ++j) {
                    d += gr[j]*pgr[j] + gi[j]*pgi[j];
                    e += gr[j]*pgi[j] - gi[j]*pgr[j];
                }
                d += lx<1>(d); e += lx<1>(e);
                d += lx<2>(d); e += lx<2>(e);
                float g2 = d*d + e*e;
                float cth = 1.f, sth = 0.f, cph = 1.f, sph = 0.f, gn = 0.f;
                if (g2 > 1e-26f) {
                    gn = __builtin_amdgcn_sqrtf(g2);
                    float ginv = __builtin_amdgcn_rcpf(gn);
                    cph = d * ginv; sph = -e * ginv;
                    float tau = (alm - bep) * (0.5f * ginv);
                    float tt = ((tau >= 0.f) ? 1.f : -1.f) *
                               __builtin_amdgcn_rcpf(fabsf(tau) + __builtin_amdgcn_sqrtf(1.f + tau*tau));
                    cth = __builtin_amdgcn_rsqf(1.f + tt*tt);
                    sth = tt * cth;
                }
#pragma unroll
                for (int j = 0; j < 4; ++j) {
                    float er = cph*pgr[j] - sph*pgi[j];
                    float ei = cph*pgi[j] + sph*pgr[j];
                    gr[j] = cth * gr[j] + sth * er;
                    gi[j] = cth * gi[j] + sth * ei;
                }
                alm = cth*cth*alm + sth*sth*bep + 2.f*cth*sth*gn;
            }
        }

        // exact final column norm (kills approx-math drift in the running alm)
        float alm2 = 0.f;
#pragma unroll
        for (int j = 0; j < 4; ++j) alm2 += gr[j]*gr[j] + gi[j]*gi[j];
        alm2 += lx<1>(alm2);
        alm2 += lx<2>(alm2);

        float ev = fminf(fmaxf(alm2, 1e-10f), 1.0f);
        float term = -ev * __logf(ev);
#pragma unroll 1
        for (int off = 4; off < 64; off <<= 1) term += bperm_(lb4 ^ (off << 2), term);
        if (L == 0) out[BB * NC + b] = term;
    }
}

extern "C" void kernel_launch(void* const* d_in, const int* in_sizes, int n_in,
                              void* d_out, int out_size, void* d_ws, size_t ws_size,
                              hipStream_t stream) {
    const float* x    = (const float*)d_in[0];
    const float* Wemb = (const float*)d_in[1];
    const float* bemb = (const float*)d_in[2];
    const float* Wq   = (const float*)d_in[3];
    const float* bq   = (const float*)d_in[4];
    const float* Wk   = (const float*)d_in[5];
    const float* bk   = (const float*)d_in[6];
    const float* Wv   = (const float*)d_in[7];
    const float* bv   = (const float*)d_in[8];
    const float* Wo   = (const float*)d_in[9];
    const float* bo   = (const float*)d_in[10];
    const float* ln1g = (const float*)d_in[11];
    const float* ln1b = (const float*)d_in[12];
    const float* ln2g = (const float*)d_in[13];
    const float* ln2b = (const float*)d_in[14];
    const float* Wf1  = (const float*)d_in[15];
    const float* bf1  = (const float*)d_in[16];
    const float* Wf2  = (const float*)d_in[17];
    const float* bf2  = (const float*)d_in[18];
    const float* Wp1  = (const float*)d_in[19];
    const float* bp1  = (const float*)d_in[20];
    const float* Wp2  = (const float*)d_in[21];
    const float* bp2  = (const float*)d_in[22];
    const float* qwts = (const float*)d_in[23];
    float* out = (float*)d_out;

    const size_t M = 1u << 20;           // 1M floats = B*S*D
    float* ws   = (float*)d_ws;
    float* h    = ws;                            // 1M floats
    hf2*   qh   = (hf2*)(ws + M);                // 0.5M floats (BHS*8 halves)
    hf2*   kh   = (hf2*)(ws + M + M / 2);        // 0.5M floats
    hf2*   vt   = (hf2*)(ws + 2 * M);            // 0.5M floats
    float* Ao   = ws + 2 * M + M / 2;            // 1M floats (BHS*8)

    k_qkv0<<<BB * SS / 4, 64, 0, stream>>>(x, Wemb, bemb, Wq, bq, Wk, bk, Wv, bv,
                                           qh, kh, vt, h);
    k_attn<<<dim3(BB * HH, 16), 256, 0, stream>>>((const float4*)qh, (const float4*)kh,
                                                  (const float4*)vt, Ao);
    k_mid<<<BB * SS / 4, 128, 0, stream>>>(Ao, Wo, bo, ln1g, ln1b,
                                           Wf1, bf1, Wf2, bf2, ln2g, ln2b, h, 0, 1,
                                           Wq, bq, Wk, bk, Wv, bv, qh, kh, vt);
    k_attn<<<dim3(BB * HH, 16), 256, 0, stream>>>((const float4*)qh, (const float4*)kh,
                                                  (const float4*)vt, Ao);
    k_mid<<<BB * SS / 4, 128, 0, stream>>>(Ao, Wo, bo, ln1g, ln1b,
                                           Wf1, bf1, Wf2, bf2, ln2g, ln2b, h, 1, 0,
                                           Wq, bq, Wk, bk, Wv, bv, qh, kh, vt);
    k_tail<<<BB, 256, 0, stream>>>(h, Wp1, bp1, Wp2, bp2, qwts, out);
}